// Round 1
// baseline (2211.814 us; speedup 1.0000x reference)
//
#include <hip/hip_runtime.h>
#include <math.h>

// ---- problem constants ----
#define BB 2
#define HH 16
#define NN 1024
#define CC 1024
#define DD 64
#define NPAST 8192
#define NANCH 1024
#define CBUD 4096
#define NKEEP 3072   // CBUD - NANCH
#define NCAND 8192   // (NPAST + NN) - NANCH
#define BH 32        // BB*HH

// ---- d_out layout (floats) ----
#define OUT_SZ   (BB*NN*CC)                 // 2097152
#define KNEW_OFF ((size_t)OUT_SZ)
#define KNEW_SZ  ((size_t)BH*CBUD*DD)       // 8388608
#define VNEW_OFF (KNEW_OFF + KNEW_SZ)
#define AVG_OFF  (VNEW_OFF + KNEW_SZ)       // 18874368

// ---- workspace layout (floats) ----
#define WS_Q   ((size_t)0)
#define WS_K   (WS_Q + (size_t)BH*NN*DD)    // 2097152
#define WS_V   (WS_K + (size_t)BH*NN*DD)    // 4194304
#define WS_O   (WS_V + (size_t)BH*NN*DD)    // 6291456
#define WS_MD  (WS_O + (size_t)BH*NN*DD)    // 8388608 (mean_dir 32*64)
#define WS_SC  (WS_MD + (size_t)BH*DD)      // scores 32*8192
#define WS_BS  (WS_SC + (size_t)BH*NCAND)   // per-block score sums (32)
#define WS_SEL (WS_BS + (size_t)64)         // selected idx (int) 32*3072

// ============================================================
// K1: qkv = x @ qkv_w^T + b, scattered to q/k/v (B,H,N,D) in ws
// 64x64 tile, BK=16, 256 thr, 4x4/thread, fp32.
// ============================================================
__global__ __launch_bounds__(256) void qkv_gemm(const float* __restrict__ x,
                                                const float* __restrict__ w,
                                                const float* __restrict__ bias,
                                                float* __restrict__ ws)
{
    __shared__ float As[16][68];
    __shared__ float Bs[16][68];
    int tid = threadIdx.x;
    int m0 = blockIdx.y * 64;
    int n0 = blockIdx.x * 64;
    int tx = tid & 15, ty = tid >> 4;
    int lr = tid >> 2;            // 0..63 tile row for loads
    int lk = (tid & 3) * 4;       // 0,4,8,12
    float acc[4][4] = {{0.f}};

    for (int k0 = 0; k0 < CC; k0 += 16) {
        float4 a = *(const float4*)&x[(size_t)(m0 + lr) * CC + k0 + lk];
        float4 b = *(const float4*)&w[(size_t)(n0 + lr) * CC + k0 + lk];
        __syncthreads();
        As[lk+0][lr] = a.x; As[lk+1][lr] = a.y; As[lk+2][lr] = a.z; As[lk+3][lr] = a.w;
        Bs[lk+0][lr] = b.x; Bs[lk+1][lr] = b.y; Bs[lk+2][lr] = b.z; Bs[lk+3][lr] = b.w;
        __syncthreads();
        float tacc[4][4] = {{0.f}};   // hierarchical accumulation: keeps rounding ~np-level
        #pragma unroll
        for (int kk = 0; kk < 16; ++kk) {
            float4 a4 = *(const float4*)&As[kk][ty*4];
            float4 b4 = *(const float4*)&Bs[kk][tx*4];
            float av[4] = {a4.x, a4.y, a4.z, a4.w};
            float bv[4] = {b4.x, b4.y, b4.z, b4.w};
            #pragma unroll
            for (int i = 0; i < 4; ++i)
                #pragma unroll
                for (int j = 0; j < 4; ++j)
                    tacc[i][j] += av[i] * bv[j];
        }
        #pragma unroll
        for (int i = 0; i < 4; ++i)
            #pragma unroll
            for (int j = 0; j < 4; ++j)
                acc[i][j] += tacc[i][j];
    }

    // epilogue: add bias, scatter to q/k/v (B,H,N,D)
    int cn0 = n0 + tx * 4;                 // whole 64-col tile is one (which,h)
    int which = cn0 >> 10;
    int wc = cn0 & 1023;
    int h = wc >> 6, dd0 = wc & 63;
    float4 b4 = *(const float4*)&bias[cn0];
    float* base = ws + (which == 0 ? WS_Q : (which == 1 ? WS_K : WS_V));
    #pragma unroll
    for (int i = 0; i < 4; ++i) {
        int m = m0 + ty * 4 + i;
        int b = m >> 10, n = m & 1023;
        float4 t;
        t.x = acc[i][0] + b4.x; t.y = acc[i][1] + b4.y;
        t.z = acc[i][2] + b4.z; t.w = acc[i][3] + b4.w;
        *(float4*)&base[(((size_t)b*HH + h)*NN + n)*DD + dd0] = t;
    }
}

// ============================================================
// K2a: mean_dir[bh][d] = mean over 8192 candidates of khat
// ============================================================
__global__ __launch_bounds__(256) void meandir_k(const float* __restrict__ past_k,
                                                 float* __restrict__ ws)
{
    int bh = blockIdx.x, tid = threadIdx.x;
    const float* kpast = past_k + (size_t)bh * NPAST * DD;
    const float* knew  = ws + WS_K + (size_t)bh * NN * DD;
    float dir[64];
    #pragma unroll
    for (int i = 0; i < 64; ++i) dir[i] = 0.f;

    for (int j = tid; j < NCAND; j += 256) {
        int pos = NANCH + j;
        const float* row = (pos < NPAST) ? (kpast + (size_t)pos * DD)
                                         : (knew + (size_t)(pos - NPAST) * DD);
        float v[64]; float ss = 0.f;
        #pragma unroll
        for (int g = 0; g < 16; ++g) {
            float4 t = *(const float4*)&row[g*4];
            v[4*g]=t.x; v[4*g+1]=t.y; v[4*g+2]=t.z; v[4*g+3]=t.w;
            ss += t.x*t.x + t.y*t.y + t.z*t.z + t.w*t.w;
        }
        float inv = 1.0f / (sqrtf(ss) + 1e-6f);
        #pragma unroll
        for (int i = 0; i < 64; ++i) dir[i] += v[i] * inv;
    }
    // wave butterfly reduce each dim
    #pragma unroll
    for (int i = 0; i < 64; ++i)
        for (int off = 32; off; off >>= 1) dir[i] += __shfl_xor(dir[i], off);

    __shared__ float sdir[4][64];
    int lane = tid & 63, wid = tid >> 6;
    if (lane == 0) {
        #pragma unroll
        for (int i = 0; i < 64; ++i) sdir[wid][i] = dir[i];
    }
    __syncthreads();
    if (tid < 64) {
        float s = sdir[0][tid] + sdir[1][tid] + sdir[2][tid] + sdir[3][tid];
        ws[WS_MD + (size_t)bh*DD + tid] = s * (1.0f / (float)NCAND);
    }
}

// ============================================================
// K2b: scores[bh][j] = khat_j . mean_dir ; block sum for avg
// ============================================================
__global__ __launch_bounds__(256) void scores_k(const float* __restrict__ past_k,
                                                float* __restrict__ ws)
{
    __shared__ float md[64];
    __shared__ float sred[4];
    int bh = blockIdx.x, tid = threadIdx.x;
    if (tid < 64) md[tid] = ws[WS_MD + (size_t)bh*DD + tid];
    __syncthreads();
    const float* kpast = past_k + (size_t)bh * NPAST * DD;
    const float* knew  = ws + WS_K + (size_t)bh * NN * DD;
    float ssum = 0.f;
    for (int j = tid; j < NCAND; j += 256) {
        int pos = NANCH + j;
        const float* row = (pos < NPAST) ? (kpast + (size_t)pos * DD)
                                         : (knew + (size_t)(pos - NPAST) * DD);
        float ss = 0.f, dp = 0.f;
        #pragma unroll
        for (int g = 0; g < 16; ++g) {
            float4 t = *(const float4*)&row[g*4];
            ss += t.x*t.x + t.y*t.y + t.z*t.z + t.w*t.w;
            dp += t.x*md[4*g] + t.y*md[4*g+1] + t.z*md[4*g+2] + t.w*md[4*g+3];
        }
        float sc = dp / (sqrtf(ss) + 1e-6f);
        ws[WS_SC + (size_t)bh*NCAND + j] = sc;
        ssum += sc;
    }
    for (int off = 32; off; off >>= 1) ssum += __shfl_xor(ssum, off);
    int lane = tid & 63, wid = tid >> 6;
    if (lane == 0) sred[wid] = ssum;
    __syncthreads();
    if (tid == 0) ws[WS_BS + bh] = sred[0] + sred[1] + sred[2] + sred[3];
}

// avg_scores = mean over all
__global__ void avg_k(const float* __restrict__ ws, float* __restrict__ dout)
{
    int tid = threadIdx.x;
    float v = (tid < BH) ? ws[WS_BS + tid] : 0.f;
    for (int off = 32; off; off >>= 1) v += __shfl_xor(v, off);
    if (tid == 0) dout[AVG_OFF] = v * (1.0f / ((float)BH * (float)NCAND));
}

// ============================================================
// K3: exact radix-select of 3072 smallest scores + stable
// index-ordered compaction. One block of 1024 thr per (b,h).
// ============================================================
__global__ __launch_bounds__(1024) void topk_k(float* __restrict__ ws, int* __restrict__ sel)
{
    __shared__ unsigned keys[NCAND];   // 32 KiB
    __shared__ int red[16];
    __shared__ int red2[16];
    __shared__ int bcast;
    int bh = blockIdx.x, tid = threadIdx.x;
    int lane = tid & 63, wid = tid >> 6;

    for (int j = tid; j < NCAND; j += 1024) {
        unsigned u = __float_as_uint(ws[WS_SC + (size_t)bh*NCAND + j]);
        u ^= (u & 0x80000000u) ? 0xFFFFFFFFu : 0x80000000u;  // order-preserving map
        keys[j] = u;
    }
    __syncthreads();

    unsigned prefix = 0; int rem = NKEEP;
    for (int bit = 31; bit >= 0; --bit) {
        unsigned bm = 1u << bit;
        unsigned hm = ~((bm << 1) - 1u);   // decided-bits mask (bit=31 -> 0)
        int cnt = 0;
        for (int j = tid; j < NCAND; j += 1024) {
            unsigned k = keys[j];
            cnt += (int)(((k & hm) == prefix) & ((k & bm) == 0u));
        }
        for (int off = 32; off; off >>= 1) cnt += __shfl_xor(cnt, off);
        if (lane == 0) red[wid] = cnt;
        __syncthreads();
        if (tid == 0) { int c = 0; for (int i = 0; i < 16; ++i) c += red[i]; bcast = c; }
        __syncthreads();
        int c0 = bcast;
        if (rem <= c0) { /* bit stays 0 */ } else { rem -= c0; prefix |= bm; }
    }
    unsigned T = prefix;   // exact key value of the 3072nd smallest

    // c_less = #keys < T
    {
        int cnt = 0;
        for (int j = tid; j < NCAND; j += 1024) cnt += (int)(keys[j] < T);
        for (int off = 32; off; off >>= 1) cnt += __shfl_xor(cnt, off);
        if (lane == 0) red[wid] = cnt;
        __syncthreads();
        if (tid == 0) { int c = 0; for (int i = 0; i < 16; ++i) c += red[i]; bcast = c; }
        __syncthreads();
    }
    int c_less = bcast;
    int ttie = NKEEP - c_less;   // ties taken in index order (matches stable top_k)

    // stable compaction: thread owns 8 consecutive keys
    int base = tid * 8;
    unsigned kv[8]; int lcnt = 0, ecnt = 0;
    #pragma unroll
    for (int i = 0; i < 8; ++i) {
        kv[i] = keys[base + i];
        lcnt += (int)(kv[i] < T);
        ecnt += (int)(kv[i] == T);
    }
    int li = lcnt, ei = ecnt;
    for (int off = 1; off < 64; off <<= 1) {
        int tl = __shfl_up(li, off);
        int te = __shfl_up(ei, off);
        if (lane >= off) { li += tl; ei += te; }
    }
    __syncthreads();
    if (lane == 63) { red[wid] = li; red2[wid] = ei; }
    __syncthreads();
    int lb = 0, eb = 0;
    for (int w = 0; w < wid; ++w) { lb += red[w]; eb += red2[w]; }
    lb += li - lcnt; eb += ei - ecnt;   // exclusive prefixes
    #pragma unroll
    for (int i = 0; i < 8; ++i) {
        bool less = kv[i] < T, eq = kv[i] == T;
        if (less || (eq && eb < ttie)) {
            int pos = lb + (eb < ttie ? eb : ttie);
            sel[(size_t)bh*NKEEP + pos] = base + i;
        }
        lb += (int)less; eb += (int)eq;
    }
}

// ============================================================
// K4: gather k_new / v_new into d_out. 16 lanes per row, float4.
// ============================================================
__global__ __launch_bounds__(256) void gather_k(const float* __restrict__ past_k,
                                                const float* __restrict__ past_v,
                                                const float* __restrict__ ws,
                                                const int* __restrict__ sel,
                                                float* __restrict__ dout)
{
    int gid = blockIdx.x * 256 + threadIdx.x;
    int row = gid >> 4, lane = gid & 15;
    int bh = row >> 12, r = row & 4095;
    int pos = (r < NANCH) ? r : (NANCH + sel[(size_t)bh*NKEEP + (r - NANCH)]);
    const float *kr, *vr;
    if (pos < NPAST) {
        kr = past_k + ((size_t)bh*NPAST + pos) * DD;
        vr = past_v + ((size_t)bh*NPAST + pos) * DD;
    } else {
        kr = ws + WS_K + ((size_t)bh*NN + (pos - NPAST)) * DD;
        vr = ws + WS_V + ((size_t)bh*NN + (pos - NPAST)) * DD;
    }
    float4 kq = *(const float4*)&kr[lane*4];
    float4 vq = *(const float4*)&vr[lane*4];
    *(float4*)&dout[KNEW_OFF + ((size_t)bh*CBUD + r)*DD + lane*4] = kq;
    *(float4*)&dout[VNEW_OFF + ((size_t)bh*CBUD + r)*DD + lane*4] = vq;
}

// ============================================================
// K5: flash attention, fp32. 2 threads per q-row (32 dims each),
// 128 q-rows per 256-thr block, K/V staged 64 rows at a time.
// ============================================================
__global__ __launch_bounds__(256) void attn_k(float* __restrict__ ws,
                                              const float* __restrict__ dout)
{
    __shared__ float Ks[64][64];
    __shared__ float Vs[64][64];
    int tid = threadIdx.x;
    int bh = blockIdx.x >> 3;
    int qc = blockIdx.x & 7;
    int rl = tid >> 1, half = tid & 1, d0 = half * 32;
    int qrow = qc * 128 + rl;

    const float* qp = ws + WS_Q + ((size_t)bh*NN + qrow)*DD + d0;
    float q[32];
    #pragma unroll
    for (int g = 0; g < 8; ++g) {
        float4 t = *(const float4*)&qp[g*4];
        q[4*g]=t.x; q[4*g+1]=t.y; q[4*g+2]=t.z; q[4*g+3]=t.w;
    }
    float acc[32];
    #pragma unroll
    for (int i = 0; i < 32; ++i) acc[i] = 0.f;
    float mrun = -3.0e38f, lrun = 0.f;

    const float* kb = dout + KNEW_OFF + (size_t)bh*CBUD*DD;
    const float* vb = dout + VNEW_OFF + (size_t)bh*CBUD*DD;

    for (int c0 = 0; c0 < CBUD; c0 += 64) {
        __syncthreads();
        #pragma unroll
        for (int i = 0; i < 4; ++i) {
            int l = tid + i * 256;
            int krr = l >> 4, c4 = (l & 15) * 4;
            *(float4*)&Ks[krr][c4] = *(const float4*)&kb[(size_t)(c0+krr)*DD + c4];
            *(float4*)&Vs[krr][c4] = *(const float4*)&vb[(size_t)(c0+krr)*DD + c4];
        }
        __syncthreads();
        for (int kk = 0; kk < 64; ++kk) {
            float dot = 0.f;
            #pragma unroll
            for (int g = 0; g < 8; ++g) {
                float4 k4 = *(const float4*)&Ks[kk][d0 + g*4];
                dot += q[4*g]*k4.x + q[4*g+1]*k4.y + q[4*g+2]*k4.z + q[4*g+3]*k4.w;
            }
            dot += __shfl_xor(dot, 1);
            float s = dot * 0.125f;
            float mnew = fmaxf(mrun, s);
            float scale = __expf(mrun - mnew);
            float p = __expf(s - mnew);
            lrun = lrun * scale + p;
            mrun = mnew;
            #pragma unroll
            for (int g = 0; g < 8; ++g) {
                float4 v4 = *(const float4*)&Vs[kk][d0 + g*4];
                acc[4*g]   = acc[4*g]  *scale + p*v4.x;
                acc[4*g+1] = acc[4*g+1]*scale + p*v4.y;
                acc[4*g+2] = acc[4*g+2]*scale + p*v4.z;
                acc[4*g+3] = acc[4*g+3]*scale + p*v4.w;
            }
        }
    }
    float inv = 1.0f / lrun;
    float* op = ws + WS_O + ((size_t)bh*NN + qrow)*DD + d0;
    #pragma unroll
    for (int g = 0; g < 8; ++g) {
        float4 t;
        t.x = acc[4*g]*inv; t.y = acc[4*g+1]*inv;
        t.z = acc[4*g+2]*inv; t.w = acc[4*g+3]*inv;
        *(float4*)&op[g*4] = t;
    }
}

// ============================================================
// K6: out = o @ proj_w^T + proj_b ; o gathered from (B,H,N,D)
// ============================================================
__global__ __launch_bounds__(256) void proj_gemm(const float* __restrict__ ws,
                                                 const float* __restrict__ w,
                                                 const float* __restrict__ bias,
                                                 float* __restrict__ dout)
{
    __shared__ float As[16][68];
    __shared__ float Bs[16][68];
    int tid = threadIdx.x;
    int m0 = blockIdx.y * 64;
    int n0 = blockIdx.x * 64;
    int tx = tid & 15, ty = tid >> 4;
    int lr = tid >> 2;
    int lk = (tid & 3) * 4;
    float acc[4][4] = {{0.f}};

    int m = m0 + lr;
    int b = m >> 10, n = m & 1023;
    const float* obase = ws + WS_O;

    for (int k0 = 0; k0 < CC; k0 += 16) {
        int kcol = k0 + lk;
        int h = kcol >> 6, d = kcol & 63;   // 4 consecutive k stay in one h (4 | 64)
        float4 a = *(const float4*)&obase[(((size_t)b*HH + h)*NN + n)*DD + d];
        float4 bb = *(const float4*)&w[(size_t)(n0 + lr)*CC + kcol];
        __syncthreads();
        As[lk+0][lr] = a.x; As[lk+1][lr] = a.y; As[lk+2][lr] = a.z; As[lk+3][lr] = a.w;
        Bs[lk+0][lr] = bb.x; Bs[lk+1][lr] = bb.y; Bs[lk+2][lr] = bb.z; Bs[lk+3][lr] = bb.w;
        __syncthreads();
        float tacc[4][4] = {{0.f}};
        #pragma unroll
        for (int kk = 0; kk < 16; ++kk) {
            float4 a4 = *(const float4*)&As[kk][ty*4];
            float4 b4 = *(const float4*)&Bs[kk][tx*4];
            float av[4] = {a4.x, a4.y, a4.z, a4.w};
            float bv[4] = {b4.x, b4.y, b4.z, b4.w};
            #pragma unroll
            for (int i = 0; i < 4; ++i)
                #pragma unroll
                for (int j = 0; j < 4; ++j)
                    tacc[i][j] += av[i] * bv[j];
        }
        #pragma unroll
        for (int i = 0; i < 4; ++i)
            #pragma unroll
            for (int j = 0; j < 4; ++j)
                acc[i][j] += tacc[i][j];
    }

    int cn0 = n0 + tx * 4;
    float4 b4 = *(const float4*)&bias[cn0];
    #pragma unroll
    for (int i = 0; i < 4; ++i) {
        int mr = m0 + ty * 4 + i;
        float4 t;
        t.x = acc[i][0] + b4.x; t.y = acc[i][1] + b4.y;
        t.z = acc[i][2] + b4.z; t.w = acc[i][3] + b4.w;
        *(float4*)&dout[(size_t)mr*CC + cn0] = t;
    }
}

// ============================================================
extern "C" void kernel_launch(void* const* d_in, const int* in_sizes, int n_in,
                              void* d_out, int out_size, void* d_ws, size_t ws_size,
                              hipStream_t stream)
{
    (void)in_sizes; (void)n_in; (void)out_size; (void)ws_size;
    const float* x      = (const float*)d_in[0];
    const float* past_k = (const float*)d_in[1];
    const float* past_v = (const float*)d_in[2];
    const float* qkv_w  = (const float*)d_in[3];
    const float* qkv_b  = (const float*)d_in[4];
    const float* proj_w = (const float*)d_in[5];
    const float* proj_b = (const float*)d_in[6];
    float* out = (float*)d_out;
    float* ws  = (float*)d_ws;
    int*   sel = (int*)(ws + WS_SEL);

    qkv_gemm<<<dim3(48, 32), 256, 0, stream>>>(x, qkv_w, qkv_b, ws);
    meandir_k<<<32, 256, 0, stream>>>(past_k, ws);
    scores_k<<<32, 256, 0, stream>>>(past_k, ws);
    avg_k<<<1, 64, 0, stream>>>(ws, out);
    topk_k<<<32, 1024, 0, stream>>>(ws, sel);
    gather_k<<<8192, 256, 0, stream>>>(past_k, past_v, ws, sel, out);
    attn_k<<<256, 256, 0, stream>>>(ws, out);
    proj_gemm<<<dim3(16, 32), 256, 0, stream>>>(ws, proj_w, proj_b, out);
}

// Round 2
// 636.373 us; speedup vs baseline: 3.4757x; 3.4757x over previous
//
#include <hip/hip_runtime.h>
#include <math.h>

// ---- problem constants ----
#define BB 2
#define HH 16
#define NN 1024
#define CC 1024
#define DD 64
#define NPAST 8192
#define NANCH 1024
#define CBUD 4096
#define NKEEP 3072   // CBUD - NANCH
#define NCAND 8192   // (NPAST + NN) - NANCH
#define BH 32        // BB*HH

// ---- d_out layout (floats) ----
#define OUT_SZ   (BB*NN*CC)                 // 2097152
#define KNEW_OFF ((size_t)OUT_SZ)
#define KNEW_SZ  ((size_t)BH*CBUD*DD)       // 8388608
#define VNEW_OFF (KNEW_OFF + KNEW_SZ)
#define AVG_OFF  (VNEW_OFF + KNEW_SZ)       // 18874368

// ---- workspace layout (float offsets) ----
#define WS_KF  ((size_t)0)                  // fp32 new k  (2097152) -- dead after gather
#define WS_VF  ((size_t)2097152)            // fp32 new v  (2097152) -- dead after gather
#define WS_O   ((size_t)4194304)            // attn out fp32 (2097152)
#define WS_MD  ((size_t)6291456)            // mean_dir (2048)
#define WS_SC  ((size_t)6293504)            // scores (262144)
#define WS_BS  ((size_t)6555648)            // per-bh score sums (64)
#define WS_SEL ((size_t)6555712)            // selected idx int (98304)
#define WS_QB  ((size_t)6654016)            // q bf16 (2097152 ushorts = 1048576 floats)
#define WS_VT  ((size_t)0)                  // V^T bf16 (8388608 ushorts) OVERLAYS KF+VF
// end = 7702592 floats = 30.8 MB

typedef __attribute__((ext_vector_type(8))) short short8;
typedef __attribute__((ext_vector_type(4))) float f32x4;

__device__ inline unsigned short f2bf(float f) {
    unsigned u = __float_as_uint(f);
    unsigned r = (u + 0x7FFFu + ((u >> 16) & 1u)) >> 16;   // RNE
    return (unsigned short)r;
}
__device__ inline unsigned pack2(float a, float b) {
    return (unsigned)f2bf(a) | ((unsigned)f2bf(b) << 16);
}

// ============================================================
// K1: qkv = x @ qkv_w^T + b; Q -> bf16 ws, K/V -> fp32 ws
// ============================================================
__global__ __launch_bounds__(256) void qkv_gemm(const float* __restrict__ x,
                                                const float* __restrict__ w,
                                                const float* __restrict__ bias,
                                                float* __restrict__ ws)
{
    __shared__ float As[16][68];
    __shared__ float Bs[16][68];
    int tid = threadIdx.x;
    int m0 = blockIdx.y * 64;
    int n0 = blockIdx.x * 64;
    int tx = tid & 15, ty = tid >> 4;
    int lr = tid >> 2;
    int lk = (tid & 3) * 4;
    float acc[4][4] = {{0.f}};

    for (int k0 = 0; k0 < CC; k0 += 16) {
        float4 a = *(const float4*)&x[(size_t)(m0 + lr) * CC + k0 + lk];
        float4 b = *(const float4*)&w[(size_t)(n0 + lr) * CC + k0 + lk];
        __syncthreads();
        As[lk+0][lr] = a.x; As[lk+1][lr] = a.y; As[lk+2][lr] = a.z; As[lk+3][lr] = a.w;
        Bs[lk+0][lr] = b.x; Bs[lk+1][lr] = b.y; Bs[lk+2][lr] = b.z; Bs[lk+3][lr] = b.w;
        __syncthreads();
        float tacc[4][4] = {{0.f}};
        #pragma unroll
        for (int kk = 0; kk < 16; ++kk) {
            float4 a4 = *(const float4*)&As[kk][ty*4];
            float4 b4 = *(const float4*)&Bs[kk][tx*4];
            float av[4] = {a4.x, a4.y, a4.z, a4.w};
            float bv[4] = {b4.x, b4.y, b4.z, b4.w};
            #pragma unroll
            for (int i = 0; i < 4; ++i)
                #pragma unroll
                for (int j = 0; j < 4; ++j)
                    tacc[i][j] += av[i] * bv[j];
        }
        #pragma unroll
        for (int i = 0; i < 4; ++i)
            #pragma unroll
            for (int j = 0; j < 4; ++j)
                acc[i][j] += tacc[i][j];
    }

    int cn0 = n0 + tx * 4;
    int which = cn0 >> 10;
    int wc = cn0 & 1023;
    int h = wc >> 6, dd0 = wc & 63;
    float4 b4 = *(const float4*)&bias[cn0];
    unsigned short* qb = (unsigned short*)(ws + WS_QB);
    #pragma unroll
    for (int i = 0; i < 4; ++i) {
        int m = m0 + ty * 4 + i;
        int b = m >> 10, n = m & 1023;
        float t0 = acc[i][0] + b4.x, t1 = acc[i][1] + b4.y;
        float t2 = acc[i][2] + b4.z, t3 = acc[i][3] + b4.w;
        size_t idx = (((size_t)b*HH + h)*NN + n)*DD + dd0;
        if (which == 0) {
            ushort4 u;
            u.x = f2bf(t0); u.y = f2bf(t1); u.z = f2bf(t2); u.w = f2bf(t3);
            *(ushort4*)&qb[idx] = u;
        } else {
            float* base = ws + (which == 1 ? WS_KF : WS_VF);
            float4 t; t.x = t0; t.y = t1; t.z = t2; t.w = t3;
            *(float4*)&base[idx] = t;
        }
    }
}

// ============================================================
// K2a: mean_dir over 8192 candidates of khat
// ============================================================
__global__ __launch_bounds__(256) void meandir_k(const float* __restrict__ past_k,
                                                 float* __restrict__ ws)
{
    int bh = blockIdx.x, tid = threadIdx.x;
    const float* kpast = past_k + (size_t)bh * NPAST * DD;
    const float* knew  = ws + WS_KF + (size_t)bh * NN * DD;
    float dir[64];
    #pragma unroll
    for (int i = 0; i < 64; ++i) dir[i] = 0.f;

    for (int j = tid; j < NCAND; j += 256) {
        int pos = NANCH + j;
        const float* row = (pos < NPAST) ? (kpast + (size_t)pos * DD)
                                         : (knew + (size_t)(pos - NPAST) * DD);
        float v[64]; float ss = 0.f;
        #pragma unroll
        for (int g = 0; g < 16; ++g) {
            float4 t = *(const float4*)&row[g*4];
            v[4*g]=t.x; v[4*g+1]=t.y; v[4*g+2]=t.z; v[4*g+3]=t.w;
            ss += t.x*t.x + t.y*t.y + t.z*t.z + t.w*t.w;
        }
        float inv = 1.0f / (sqrtf(ss) + 1e-6f);
        #pragma unroll
        for (int i = 0; i < 64; ++i) dir[i] += v[i] * inv;
    }
    #pragma unroll
    for (int i = 0; i < 64; ++i)
        for (int off = 32; off; off >>= 1) dir[i] += __shfl_xor(dir[i], off);

    __shared__ float sdir[4][64];
    int lane = tid & 63, wid = tid >> 6;
    if (lane == 0) {
        #pragma unroll
        for (int i = 0; i < 64; ++i) sdir[wid][i] = dir[i];
    }
    __syncthreads();
    if (tid < 64) {
        float s = sdir[0][tid] + sdir[1][tid] + sdir[2][tid] + sdir[3][tid];
        ws[WS_MD + (size_t)bh*DD + tid] = s * (1.0f / (float)NCAND);
    }
}

// ============================================================
// K2b: scores
// ============================================================
__global__ __launch_bounds__(256) void scores_k(const float* __restrict__ past_k,
                                                float* __restrict__ ws)
{
    __shared__ float md[64];
    __shared__ float sred[4];
    int bh = blockIdx.x, tid = threadIdx.x;
    if (tid < 64) md[tid] = ws[WS_MD + (size_t)bh*DD + tid];
    __syncthreads();
    const float* kpast = past_k + (size_t)bh * NPAST * DD;
    const float* knew  = ws + WS_KF + (size_t)bh * NN * DD;
    float ssum = 0.f;
    for (int j = tid; j < NCAND; j += 256) {
        int pos = NANCH + j;
        const float* row = (pos < NPAST) ? (kpast + (size_t)pos * DD)
                                         : (knew + (size_t)(pos - NPAST) * DD);
        float ss = 0.f, dp = 0.f;
        #pragma unroll
        for (int g = 0; g < 16; ++g) {
            float4 t = *(const float4*)&row[g*4];
            ss += t.x*t.x + t.y*t.y + t.z*t.z + t.w*t.w;
            dp += t.x*md[4*g] + t.y*md[4*g+1] + t.z*md[4*g+2] + t.w*md[4*g+3];
        }
        float sc = dp / (sqrtf(ss) + 1e-6f);
        ws[WS_SC + (size_t)bh*NCAND + j] = sc;
        ssum += sc;
    }
    for (int off = 32; off; off >>= 1) ssum += __shfl_xor(ssum, off);
    int lane = tid & 63, wid = tid >> 6;
    if (lane == 0) sred[wid] = ssum;
    __syncthreads();
    if (tid == 0) ws[WS_BS + bh] = sred[0] + sred[1] + sred[2] + sred[3];
}

__global__ void avg_k(const float* __restrict__ ws, float* __restrict__ dout)
{
    int tid = threadIdx.x;
    float v = (tid < BH) ? ws[WS_BS + tid] : 0.f;
    for (int off = 32; off; off >>= 1) v += __shfl_xor(v, off);
    if (tid == 0) dout[AVG_OFF] = v * (1.0f / ((float)BH * (float)NCAND));
}

// ============================================================
// K3: exact radix-select + stable index-ordered compaction
// ============================================================
__global__ __launch_bounds__(1024) void topk_k(float* __restrict__ ws, int* __restrict__ sel)
{
    __shared__ unsigned keys[NCAND];
    __shared__ int red[16];
    __shared__ int red2[16];
    __shared__ int bcast;
    int bh = blockIdx.x, tid = threadIdx.x;
    int lane = tid & 63, wid = tid >> 6;

    for (int j = tid; j < NCAND; j += 1024) {
        unsigned u = __float_as_uint(ws[WS_SC + (size_t)bh*NCAND + j]);
        u ^= (u & 0x80000000u) ? 0xFFFFFFFFu : 0x80000000u;
        keys[j] = u;
    }
    __syncthreads();

    unsigned prefix = 0; int rem = NKEEP;
    for (int bit = 31; bit >= 0; --bit) {
        unsigned bm = 1u << bit;
        unsigned hm = ~((bm << 1) - 1u);
        int cnt = 0;
        for (int j = tid; j < NCAND; j += 1024) {
            unsigned k = keys[j];
            cnt += (int)(((k & hm) == prefix) & ((k & bm) == 0u));
        }
        for (int off = 32; off; off >>= 1) cnt += __shfl_xor(cnt, off);
        if (lane == 0) red[wid] = cnt;
        __syncthreads();
        if (tid == 0) { int c = 0; for (int i = 0; i < 16; ++i) c += red[i]; bcast = c; }
        __syncthreads();
        int c0 = bcast;
        if (rem <= c0) {} else { rem -= c0; prefix |= bm; }
        __syncthreads();
    }
    unsigned T = prefix;

    {
        int cnt = 0;
        for (int j = tid; j < NCAND; j += 1024) cnt += (int)(keys[j] < T);
        for (int off = 32; off; off >>= 1) cnt += __shfl_xor(cnt, off);
        if (lane == 0) red[wid] = cnt;
        __syncthreads();
        if (tid == 0) { int c = 0; for (int i = 0; i < 16; ++i) c += red[i]; bcast = c; }
        __syncthreads();
    }
    int c_less = bcast;
    int ttie = NKEEP - c_less;

    int base = tid * 8;
    unsigned kv[8]; int lcnt = 0, ecnt = 0;
    #pragma unroll
    for (int i = 0; i < 8; ++i) {
        kv[i] = keys[base + i];
        lcnt += (int)(kv[i] < T);
        ecnt += (int)(kv[i] == T);
    }
    int li = lcnt, ei = ecnt;
    for (int off = 1; off < 64; off <<= 1) {
        int tl = __shfl_up(li, off);
        int te = __shfl_up(ei, off);
        if (lane >= off) { li += tl; ei += te; }
    }
    __syncthreads();
    if (lane == 63) { red[wid] = li; red2[wid] = ei; }
    __syncthreads();
    int lb = 0, eb = 0;
    for (int w = 0; w < wid; ++w) { lb += red[w]; eb += red2[w]; }
    lb += li - lcnt; eb += ei - ecnt;
    #pragma unroll
    for (int i = 0; i < 8; ++i) {
        bool less = kv[i] < T, eq = kv[i] == T;
        if (less || (eq && eb < ttie)) {
            int pos = lb + (eb < ttie ? eb : ttie);
            sel[(size_t)bh*NKEEP + pos] = base + i;
        }
        lb += (int)less; eb += (int)eq;
    }
}

// ============================================================
// K4: gather k_new / v_new (fp32, exact) into d_out
// ============================================================
__global__ __launch_bounds__(256) void gather_k(const float* __restrict__ past_k,
                                                const float* __restrict__ past_v,
                                                const float* __restrict__ ws,
                                                const int* __restrict__ sel,
                                                float* __restrict__ dout)
{
    int gid = blockIdx.x * 256 + threadIdx.x;
    int row = gid >> 4, lane = gid & 15;
    int bh = row >> 12, r = row & 4095;
    int pos = (r < NANCH) ? r : (NANCH + sel[(size_t)bh*NKEEP + (r - NANCH)]);
    const float *kr, *vr;
    if (pos < NPAST) {
        kr = past_k + ((size_t)bh*NPAST + pos) * DD;
        vr = past_v + ((size_t)bh*NPAST + pos) * DD;
    } else {
        kr = ws + WS_KF + ((size_t)bh*NN + (pos - NPAST)) * DD;
        vr = ws + WS_VF + ((size_t)bh*NN + (pos - NPAST)) * DD;
    }
    float4 kq = *(const float4*)&kr[lane*4];
    float4 vq = *(const float4*)&vr[lane*4];
    *(float4*)&dout[KNEW_OFF + ((size_t)bh*CBUD + r)*DD + lane*4] = kq;
    *(float4*)&dout[VNEW_OFF + ((size_t)bh*CBUD + r)*DD + lane*4] = vq;
}

// ============================================================
// K4b: V^T bf16: vt[bh][d][key] from v_new fp32 (for PV B-frags)
// ============================================================
__global__ __launch_bounds__(256) void vtrans_k(const float* __restrict__ dout,
                                                unsigned short* __restrict__ vt)
{
    __shared__ unsigned short S[64][65];
    int bh = blockIdx.x >> 6, kt = blockIdx.x & 63;
    int c0 = kt * 64;
    int tid = threadIdx.x;
    int r = tid >> 2, c4 = (tid & 3) * 16;
    const float* src = dout + VNEW_OFF + ((size_t)bh*CBUD + c0 + r)*DD + c4;
    #pragma unroll
    for (int i = 0; i < 4; ++i) {
        float4 f = *(const float4*)&src[i*4];
        S[r][c4 + i*4 + 0] = f2bf(f.x);
        S[r][c4 + i*4 + 1] = f2bf(f.y);
        S[r][c4 + i*4 + 2] = f2bf(f.z);
        S[r][c4 + i*4 + 3] = f2bf(f.w);
    }
    __syncthreads();
    int d = r, k4 = c4;
    uint4 u0, u1;
    u0.x = (unsigned)S[k4+0][d] | ((unsigned)S[k4+1][d] << 16);
    u0.y = (unsigned)S[k4+2][d] | ((unsigned)S[k4+3][d] << 16);
    u0.z = (unsigned)S[k4+4][d] | ((unsigned)S[k4+5][d] << 16);
    u0.w = (unsigned)S[k4+6][d] | ((unsigned)S[k4+7][d] << 16);
    u1.x = (unsigned)S[k4+8][d] | ((unsigned)S[k4+9][d] << 16);
    u1.y = (unsigned)S[k4+10][d] | ((unsigned)S[k4+11][d] << 16);
    u1.z = (unsigned)S[k4+12][d] | ((unsigned)S[k4+13][d] << 16);
    u1.w = (unsigned)S[k4+14][d] | ((unsigned)S[k4+15][d] << 16);
    unsigned short* dst = vt + ((size_t)bh*DD + d)*CBUD + c0 + k4;
    *(uint4*)&dst[0] = u0;
    *(uint4*)&dst[8] = u1;
}

// ============================================================
// K5: MFMA flash attention (bf16 inputs, fp32 accum)
// 4 waves x 16 q-rows = 64-row Q tile; KV tiles of 64.
// ============================================================
__global__ __launch_bounds__(256) void attn_mfma(const unsigned short* __restrict__ qb,
                                                 const float* __restrict__ dout,
                                                 const unsigned short* __restrict__ vt,
                                                 float* __restrict__ o_out)
{
    __shared__ char kls[8192];       // K tile [64 keys][128B] swizzled
    __shared__ char vls[8192];       // V^T tile [64 d][128B] swizzled
    __shared__ char pls[4][2048];    // per-wave P [16 q][128B] swizzled

    int orig = blockIdx.x;
    int bid = (orig & 7) * 64 + (orig >> 3);      // XCD-chunked swizzle (512 = 8*64)
    int bh = bid >> 4, qt = bid & 15;
    int tid = threadIdx.x;
    int w = tid >> 6, lane = tid & 63;
    int g = lane >> 4, r16 = lane & 15;
    int q0 = qt * 64 + w * 16;

    const float* kn = dout + KNEW_OFF + (size_t)bh * CBUD * DD;
    const unsigned short* vtb = vt + (size_t)bh * DD * CBUD;

    // Q fragments (A): row = r16, k = 8g+j (+32 for slot 1)
    const unsigned short* qrow = qb + ((size_t)bh*NN + q0 + r16) * DD;
    short8 qa0 = *(const short8*)&qrow[8*g];
    short8 qa1 = *(const short8*)&qrow[32 + 8*g];

    f32x4 accd[4];
    #pragma unroll
    for (int dt = 0; dt < 4; ++dt) accd[dt] = 0.f;
    float mreg[4] = {-3.0e38f, -3.0e38f, -3.0e38f, -3.0e38f};
    float lreg[4] = {0.f, 0.f, 0.f, 0.f};

    for (int c0 = 0; c0 < CBUD; c0 += 64) {
        __syncthreads();
        // stage K (fp32 -> bf16) and V^T (bf16 copy), both XOR-swizzled
        #pragma unroll
        for (int i = 0; i < 2; ++i) {
            int o = (tid + 256*i) * 16;
            int row = o >> 7, cb = o & 127;
            const float* s = kn + (size_t)(c0 + row)*DD + (cb >> 1);
            float4 f0 = *(const float4*)s;
            float4 f1 = *(const float4*)(s + 4);
            uint4 u;
            u.x = pack2(f0.x, f0.y); u.y = pack2(f0.z, f0.w);
            u.z = pack2(f1.x, f1.y); u.w = pack2(f1.z, f1.w);
            *(uint4*)&kls[o ^ ((row & 7) << 4)] = u;
            const unsigned short* sv = vtb + (size_t)row*CBUD + c0 + (cb >> 1);
            *(uint4*)&vls[o ^ ((row & 7) << 4)] = *(const uint4*)sv;
        }
        __syncthreads();

        // QK^T: S[16q][64keys] as 4 16-key subtiles
        f32x4 sacc[4];
        #pragma unroll
        for (int t = 0; t < 4; ++t) sacc[t] = 0.f;
        #pragma unroll
        for (int t = 0; t < 4; ++t) {
            int krow = t*16 + r16;
            int ksw = (krow & 7) << 4;
            short8 kb0 = *(const short8*)&kls[(krow*128 + 16*g)      ^ ksw];
            short8 kb1 = *(const short8*)&kls[(krow*128 + 16*g + 64) ^ ksw];
            sacc[t] = __builtin_amdgcn_mfma_f32_16x16x32_bf16(qa0, kb0, sacc[t], 0, 0, 0);
            sacc[t] = __builtin_amdgcn_mfma_f32_16x16x32_bf16(qa1, kb1, sacc[t], 0, 0, 0);
        }

        // online softmax: lane holds S[q=4g+rr][key=c0 + 16t + r16]
        #pragma unroll
        for (int rr = 0; rr < 4; ++rr) {
            float s0 = sacc[0][rr]*0.125f, s1 = sacc[1][rr]*0.125f;
            float s2 = sacc[2][rr]*0.125f, s3 = sacc[3][rr]*0.125f;
            float mt = fmaxf(fmaxf(s0, s1), fmaxf(s2, s3));
            mt = fmaxf(mt, __shfl_xor(mt, 1));
            mt = fmaxf(mt, __shfl_xor(mt, 2));
            mt = fmaxf(mt, __shfl_xor(mt, 4));
            mt = fmaxf(mt, __shfl_xor(mt, 8));
            float mnew = fmaxf(mreg[rr], mt);
            float resc = __expf(mreg[rr] - mnew);
            float p0 = __expf(s0 - mnew), p1 = __expf(s1 - mnew);
            float p2 = __expf(s2 - mnew), p3 = __expf(s3 - mnew);
            float ps = p0 + p1 + p2 + p3;
            ps += __shfl_xor(ps, 1);
            ps += __shfl_xor(ps, 2);
            ps += __shfl_xor(ps, 4);
            ps += __shfl_xor(ps, 8);
            lreg[rr] = lreg[rr]*resc + ps;
            mreg[rr] = mnew;
            accd[0][rr] *= resc; accd[1][rr] *= resc;
            accd[2][rr] *= resc; accd[3][rr] *= resc;
            // write P row (q-local 4g+rr) as bf16, swizzled
            int prow = 4*g + rr;
            int psw = (prow & 7) << 4;
            int pb = prow * 128;
            *(unsigned short*)&pls[w][(pb + (r16     )*2) ^ psw] = f2bf(p0);
            *(unsigned short*)&pls[w][(pb + (r16 + 16)*2) ^ psw] = f2bf(p1);
            *(unsigned short*)&pls[w][(pb + (r16 + 32)*2) ^ psw] = f2bf(p2);
            *(unsigned short*)&pls[w][(pb + (r16 + 48)*2) ^ psw] = f2bf(p3);
        }

        // PV: A = P (row=r16, k=keys), B = V^T rows
        int asw = (r16 & 7) << 4;
        short8 pa0 = *(const short8*)&pls[w][(r16*128 + 16*g)      ^ asw];
        short8 pa1 = *(const short8*)&pls[w][(r16*128 + 16*g + 64) ^ asw];
        #pragma unroll
        for (int dt = 0; dt < 4; ++dt) {
            int vrow = dt*16 + r16;
            int vsw = (vrow & 7) << 4;
            short8 vb0 = *(const short8*)&vls[(vrow*128 + 16*g)      ^ vsw];
            short8 vb1 = *(const short8*)&vls[(vrow*128 + 16*g + 64) ^ vsw];
            accd[dt] = __builtin_amdgcn_mfma_f32_16x16x32_bf16(pa0, vb0, accd[dt], 0, 0, 0);
            accd[dt] = __builtin_amdgcn_mfma_f32_16x16x32_bf16(pa1, vb1, accd[dt], 0, 0, 0);
        }
    }

    float invl[4];
    #pragma unroll
    for (int rr = 0; rr < 4; ++rr) invl[rr] = 1.0f / lreg[rr];
    #pragma unroll
    for (int dt = 0; dt < 4; ++dt)
        #pragma unroll
        for (int rr = 0; rr < 4; ++rr)
            o_out[((size_t)bh*NN + q0 + 4*g + rr)*DD + dt*16 + r16] = accd[dt][rr] * invl[rr];
}

// ============================================================
// K6: out = o @ proj_w^T + proj_b
// ============================================================
__global__ __launch_bounds__(256) void proj_gemm(const float* __restrict__ ws,
                                                 const float* __restrict__ w,
                                                 const float* __restrict__ bias,
                                                 float* __restrict__ dout)
{
    __shared__ float As[16][68];
    __shared__ float Bs[16][68];
    int tid = threadIdx.x;
    int m0 = blockIdx.y * 64;
    int n0 = blockIdx.x * 64;
    int tx = tid & 15, ty = tid >> 4;
    int lr = tid >> 2;
    int lk = (tid & 3) * 4;
    float acc[4][4] = {{0.f}};

    int m = m0 + lr;
    int b = m >> 10, n = m & 1023;
    const float* obase = ws + WS_O;

    for (int k0 = 0; k0 < CC; k0 += 16) {
        int kcol = k0 + lk;
        int h = kcol >> 6, d = kcol & 63;
        float4 a = *(const float4*)&obase[(((size_t)b*HH + h)*NN + n)*DD + d];
        float4 bb = *(const float4*)&w[(size_t)(n0 + lr)*CC + kcol];
        __syncthreads();
        As[lk+0][lr] = a.x; As[lk+1][lr] = a.y; As[lk+2][lr] = a.z; As[lk+3][lr] = a.w;
        Bs[lk+0][lr] = bb.x; Bs[lk+1][lr] = bb.y; Bs[lk+2][lr] = bb.z; Bs[lk+3][lr] = bb.w;
        __syncthreads();
        float tacc[4][4] = {{0.f}};
        #pragma unroll
        for (int kk = 0; kk < 16; ++kk) {
            float4 a4 = *(const float4*)&As[kk][ty*4];
            float4 b4 = *(const float4*)&Bs[kk][tx*4];
            float av[4] = {a4.x, a4.y, a4.z, a4.w};
            float bv[4] = {b4.x, b4.y, b4.z, b4.w};
            #pragma unroll
            for (int i = 0; i < 4; ++i)
                #pragma unroll
                for (int j = 0; j < 4; ++j)
                    tacc[i][j] += av[i] * bv[j];
        }
        #pragma unroll
        for (int i = 0; i < 4; ++i)
            #pragma unroll
            for (int j = 0; j < 4; ++j)
                acc[i][j] += tacc[i][j];
    }

    int cn0 = n0 + tx * 4;
    float4 b4 = *(const float4*)&bias[cn0];
    #pragma unroll
    for (int i = 0; i < 4; ++i) {
        int mr = m0 + ty * 4 + i;
        float4 t;
        t.x = acc[i][0] + b4.x; t.y = acc[i][1] + b4.y;
        t.z = acc[i][2] + b4.z; t.w = acc[i][3] + b4.w;
        *(float4*)&dout[(size_t)mr*CC + cn0] = t;
    }
}

// ============================================================
extern "C" void kernel_launch(void* const* d_in, const int* in_sizes, int n_in,
                              void* d_out, int out_size, void* d_ws, size_t ws_size,
                              hipStream_t stream)
{
    (void)in_sizes; (void)n_in; (void)out_size; (void)ws_size;
    const float* x      = (const float*)d_in[0];
    const float* past_k = (const float*)d_in[1];
    const float* past_v = (const float*)d_in[2];
    const float* qkv_w  = (const float*)d_in[3];
    const float* qkv_b  = (const float*)d_in[4];
    const float* proj_w = (const float*)d_in[5];
    const float* proj_b = (const float*)d_in[6];
    float* out = (float*)d_out;
    float* ws  = (float*)d_ws;
    int*   sel = (int*)(ws + WS_SEL);
    unsigned short* qbp = (unsigned short*)(ws + WS_QB);
    unsigned short* vtp = (unsigned short*)(ws + WS_VT);

    qkv_gemm<<<dim3(48, 32), 256, 0, stream>>>(x, qkv_w, qkv_b, ws);
    meandir_k<<<32, 256, 0, stream>>>(past_k, ws);
    scores_k<<<32, 256, 0, stream>>>(past_k, ws);
    avg_k<<<1, 64, 0, stream>>>(ws, out);
    topk_k<<<32, 1024, 0, stream>>>(ws, sel);
    gather_k<<<8192, 256, 0, stream>>>(past_k, past_v, ws, sel, out);
    vtrans_k<<<2048, 256, 0, stream>>>(out, vtp);
    attn_mfma<<<512, 256, 0, stream>>>(qbp, out, vtp, ws + WS_O);
    proj_gemm<<<dim3(16, 32), 256, 0, stream>>>(ws, proj_w, proj_b, out);
}

// Round 5
// 411.424 us; speedup vs baseline: 5.3760x; 1.5468x over previous
//
#include <hip/hip_runtime.h>
#include <hip/hip_bf16.h>
#include <math.h>

// ---- problem constants ----
#define BB 2
#define HH 16
#define NN 1024
#define CC 1024
#define DD 64
#define NPAST 8192
#define NANCH 1024
#define CBUD 4096
#define NKEEP 3072
#define NCAND 8192
#define BH 32

// tiled bf16 layout: K-chunk tile = 128 rows x 64 k x 2B = 16384 bytes
#define TILEB 16384

// ---- d_out layout (floats) ----
#define OUT_SZ   (BB*NN*CC)
#define KNEW_OFF ((size_t)OUT_SZ)
#define KNEW_SZ  ((size_t)BH*CBUD*DD)
#define VNEW_OFF (KNEW_OFF + KNEW_SZ)
#define AVG_OFF  (VNEW_OFF + KNEW_SZ)

// ---- workspace layout (float offsets), with overlays ----
#define WS_KF   ((size_t)0)            // 2097152 f
#define WS_VF   ((size_t)2097152)     // 2097152 f
#define WS_VT   ((size_t)0)            // bf16 V^T overlay (after gather)
#define WS_XT   ((size_t)4194304)     // x tiled bf16: 1048576 f
#define WS_OT   ((size_t)4194304)     // o tiled bf16 (overlay XT)
#define WS_WQVT ((size_t)5242880)     // w(Q,V) tiled bf16: 1048576 f
#define WS_WPT  ((size_t)5242880)     // proj_w tiled bf16 (overlay)
#define WS_QB   ((size_t)6291456)     // q bf16: 1048576 f
#define WS_MD   ((size_t)7340032)
#define WS_SC   ((size_t)7342080)
#define WS_BS   ((size_t)7604224)
#define WS_SEL  ((size_t)7604288)
// end = 7628864 floats = 30.5 MB

typedef __attribute__((ext_vector_type(8))) short short8;
typedef __attribute__((ext_vector_type(4))) float f32x4;

typedef unsigned int __attribute__((address_space(3))) lds_uint;
typedef unsigned int __attribute__((address_space(1))) glb_uint;

__device__ __forceinline__ void gload16(const void* g, void* l) {
    __builtin_amdgcn_global_load_lds((const glb_uint*)g, (lds_uint*)l, 16, 0, 0);
}

__device__ inline unsigned short f2bf(float f) {
    unsigned u = __float_as_uint(f);
    unsigned r = (u + 0x7FFFu + ((u >> 16) & 1u)) >> 16;
    return (unsigned short)r;
}
__device__ inline unsigned cvtpk(float a, float b) {
    __hip_bfloat162 h = __float22bfloat162_rn(make_float2(a, b));
    return *reinterpret_cast<unsigned*>(&h);
}

// ============================================================
// converters: fp32 row-major -> tiled swizzled bf16
// tile = (row>>7)*16 + (k>>6); inner = ((row&127)*128 + (k&63)*2) ^ ((row&7)<<4)
// ============================================================
__global__ __launch_bounds__(256) void conv_tile(const float* __restrict__ src,
                                                 unsigned short* __restrict__ dst)
{
    int gid = blockIdx.x * 256 + threadIdx.x;
    int r = gid >> 7, k0 = (gid & 127) * 8;
    float4 a = *(const float4*)&src[(size_t)r * 1024 + k0];
    float4 b = *(const float4*)&src[(size_t)r * 1024 + k0 + 4];
    uint4 u;
    u.x = cvtpk(a.x, a.y); u.y = cvtpk(a.z, a.w);
    u.z = cvtpk(b.x, b.y); u.w = cvtpk(b.z, b.w);
    size_t tile = (size_t)(r >> 7) * 16 + (k0 >> 6);
    int inner = (((r & 127) * 128 + (k0 & 63) * 2)) ^ ((r & 7) << 4);
    *(uint4*)((char*)dst + tile * TILEB + inner) = u;
}

// Q/V rows of qkv_w: n<1024 -> row n (Q), n>=1024 -> row n+1024 (V)
__global__ __launch_bounds__(256) void conv_wqv(const float* __restrict__ src,
                                                unsigned short* __restrict__ dst)
{
    int gid = blockIdx.x * 256 + threadIdx.x;
    int n = gid >> 7, k0 = (gid & 127) * 8;
    int srow = (n < 1024) ? n : n + 1024;
    float4 a = *(const float4*)&src[(size_t)srow * 1024 + k0];
    float4 b = *(const float4*)&src[(size_t)srow * 1024 + k0 + 4];
    uint4 u;
    u.x = cvtpk(a.x, a.y); u.y = cvtpk(a.z, a.w);
    u.z = cvtpk(b.x, b.y); u.w = cvtpk(b.z, b.w);
    size_t tile = (size_t)(n >> 7) * 16 + (k0 >> 6);
    int inner = (((n & 127) * 128 + (k0 & 63) * 2)) ^ ((n & 7) << 4);
    *(uint4*)((char*)dst + tile * TILEB + inner) = u;
}

// ============================================================
// fp32 GEMM for K-third (precision-critical ranking path).
// ============================================================
__global__ __launch_bounds__(256) void kf_gemm(const float* __restrict__ x,
                                               const float* __restrict__ w,
                                               const float* __restrict__ bias,
                                               float* __restrict__ ws)
{
    __shared__ float As[16][68];
    __shared__ float Bs[16][68];
    int tid = threadIdx.x;
    int m0 = blockIdx.y * 64;
    int n0 = blockIdx.x * 64;
    int tx = tid & 15, ty = tid >> 4;
    int lr = tid >> 2;
    int lk = (tid & 3) * 4;
    float acc[4][4] = {{0.f}};

    for (int k0 = 0; k0 < CC; k0 += 16) {
        float4 a = *(const float4*)&x[(size_t)(m0 + lr) * CC + k0 + lk];
        float4 b = *(const float4*)&w[(size_t)(1024 + n0 + lr) * CC + k0 + lk];
        __syncthreads();
        As[lk+0][lr] = a.x; As[lk+1][lr] = a.y; As[lk+2][lr] = a.z; As[lk+3][lr] = a.w;
        Bs[lk+0][lr] = b.x; Bs[lk+1][lr] = b.y; Bs[lk+2][lr] = b.z; Bs[lk+3][lr] = b.w;
        __syncthreads();
        float tacc[4][4] = {{0.f}};
        #pragma unroll
        for (int kk = 0; kk < 16; ++kk) {
            float4 a4 = *(const float4*)&As[kk][ty*4];
            float4 b4 = *(const float4*)&Bs[kk][tx*4];
            float av[4] = {a4.x, a4.y, a4.z, a4.w};
            float bv[4] = {b4.x, b4.y, b4.z, b4.w};
            #pragma unroll
            for (int i = 0; i < 4; ++i)
                #pragma unroll
                for (int j = 0; j < 4; ++j)
                    tacc[i][j] += av[i] * bv[j];
        }
        #pragma unroll
        for (int i = 0; i < 4; ++i)
            #pragma unroll
            for (int j = 0; j < 4; ++j)
                acc[i][j] += tacc[i][j];
    }

    int cn0 = n0 + tx * 4;
    int h = cn0 >> 6, dd0 = cn0 & 63;
    float4 b4 = *(const float4*)&bias[1024 + cn0];
    float* kf = ws + WS_KF;
    #pragma unroll
    for (int i = 0; i < 4; ++i) {
        int m = m0 + ty * 4 + i;
        int b = m >> 10, n = m & 1023;
        float4 t;
        t.x = acc[i][0] + b4.x; t.y = acc[i][1] + b4.y;
        t.z = acc[i][2] + b4.z; t.w = acc[i][3] + b4.w;
        *(float4*)&kf[(((size_t)b*HH + h)*NN + n)*DD + dd0] = t;
    }
}

// ============================================================
// bf16 MFMA GEMM, 128x128 tile, BK=64, pre-tiled swizzled inputs,
// global_load_lds staging, stage-ahead + 1 barrier/step.
// MODE 0: QV epilogue (Q->bf16 qb, V->fp32 vf). MODE 1: proj -> dout.
// ============================================================
template<int MODE>
__global__ __launch_bounds__(256) void mfma_gemm(const unsigned short* __restrict__ At,
                                                 const unsigned short* __restrict__ Bt,
                                                 const float* __restrict__ bias,
                                                 float* __restrict__ outp)
{
    __shared__ char lds[131072];
    int tid = threadIdx.x;
    int w = tid >> 6, lane = tid & 63;
    int g = lane >> 4, r16 = lane & 15;
    int wr = w >> 1, wc = w & 1;
    int bm = blockIdx.y, bn = blockIdx.x;
    const int KB = 16;

    f32x4 acc[4][4];
    #pragma unroll
    for (int i = 0; i < 4; ++i)
        #pragma unroll
        for (int j = 0; j < 4; ++j) acc[i][j] = 0.f;

    const char* Abase = (const char*)At + (size_t)bm * KB * TILEB;
    const char* Bbase = (const char*)Bt + (size_t)bn * KB * TILEB;

    // prologue: stage kb=0 into buf 0 (A at 0, B at 16384)
    #pragma unroll
    for (int i = 0; i < 4; ++i) {
        gload16(Abase + (size_t)w*4096 + i*1024 + lane*16, lds + w*4096 + i*1024);
        gload16(Bbase + (size_t)w*4096 + i*1024 + lane*16, lds + TILEB + w*4096 + i*1024);
    }
    asm volatile("s_waitcnt vmcnt(0)" ::: "memory");
    __syncthreads();

    int cur = 0;
    for (int kb = 0; kb < KB; ++kb) {
        char* Acur = lds + cur * (2*TILEB);
        char* Bcur = Acur + TILEB;
        if (kb + 1 < KB) {
            char* Anxt = lds + (cur ^ 1) * (2*TILEB);
            char* Bnxt = Anxt + TILEB;
            const char* an = Abase + (size_t)(kb+1)*TILEB + w*4096;
            const char* bsrc = Bbase + (size_t)(kb+1)*TILEB + w*4096;
            #pragma unroll
            for (int i = 0; i < 4; ++i) {
                gload16(an + i*1024 + lane*16, Anxt + w*4096 + i*1024);
                gload16(bsrc + i*1024 + lane*16, Bnxt + w*4096 + i*1024);
            }
        }
        short8 a0[4], a1[4], b0[4], b1[4];
        #pragma unroll
        for (int mi = 0; mi < 4; ++mi) {
            int row = wr*64 + mi*16 + r16;
            int sw = (row & 7) << 4;
            a0[mi] = *(const short8*)(Acur + ((row*128 + g*16) ^ sw));
            a1[mi] = *(const short8*)(Acur + ((row*128 + 64 + g*16) ^ sw));
        }
        #pragma unroll
        for (int ni = 0; ni < 4; ++ni) {
            int row = wc*64 + ni*16 + r16;
            int sw = (row & 7) << 4;
            b0[ni] = *(const short8*)(Bcur + ((row*128 + g*16) ^ sw));
            b1[ni] = *(const short8*)(Bcur + ((row*128 + 64 + g*16) ^ sw));
        }
        #pragma unroll
        for (int mi = 0; mi < 4; ++mi)
            #pragma unroll
            for (int ni = 0; ni < 4; ++ni) {
                acc[mi][ni] = __builtin_amdgcn_mfma_f32_16x16x32_bf16(a0[mi], b0[ni], acc[mi][ni], 0, 0, 0);
                acc[mi][ni] = __builtin_amdgcn_mfma_f32_16x16x32_bf16(a1[mi], b1[ni], acc[mi][ni], 0, 0, 0);
            }
        asm volatile("s_waitcnt vmcnt(0)" ::: "memory");
        __syncthreads();
        cur ^= 1;
    }

    // epilogue
    int nq = bn*128 + wc*64;
    float bv[4];
    #pragma unroll
    for (int ni = 0; ni < 4; ++ni) {
        int n = nq + ni*16 + r16;
        bv[ni] = (MODE == 0) ? bias[(n < 1024) ? n : (n + 1024)] : bias[n];
    }
    #pragma unroll
    for (int mi = 0; mi < 4; ++mi) {
        #pragma unroll
        for (int rr = 0; rr < 4; ++rr) {
            int ml = wr*64 + mi*16 + 4*g + rr;
            int mg = bm*128 + ml;
            int bb = mg >> 10, tok = mg & 1023;
            #pragma unroll
            for (int ni = 0; ni < 4; ++ni) {
                int n = nq + ni*16 + r16;
                float v = acc[mi][ni][rr] + bv[ni];
                if (MODE == 0) {
                    if (n < 1024) {
                        unsigned short* qb = (unsigned short*)(outp + WS_QB);
                        int hh = n >> 6, d = n & 63;
                        qb[(((size_t)bb*16 + hh)*1024 + tok)*64 + d] = f2bf(v);
                    } else {
                        float* vf = outp + WS_VF;
                        int hh = (n - 1024) >> 6, d = n & 63;
                        vf[(((size_t)bb*16 + hh)*1024 + tok)*64 + d] = v;
                    }
                } else {
                    outp[(size_t)mg*1024 + n] = v;
                }
            }
        }
    }
}

// ============================================================
// mean_dir over 8192 candidates of khat
// ============================================================
__global__ __launch_bounds__(256) void meandir_k(const float* __restrict__ past_k,
                                                 float* __restrict__ ws)
{
    int bh = blockIdx.x, tid = threadIdx.x;
    const float* kpast = past_k + (size_t)bh * NPAST * DD;
    const float* knew  = ws + WS_KF + (size_t)bh * NN * DD;
    float dir[64];
    #pragma unroll
    for (int i = 0; i < 64; ++i) dir[i] = 0.f;

    for (int j = tid; j < NCAND; j += 256) {
        int pos = NANCH + j;
        const float* row = (pos < NPAST) ? (kpast + (size_t)pos * DD)
                                         : (knew + (size_t)(pos - NPAST) * DD);
        float v[64]; float ss = 0.f;
        #pragma unroll
        for (int g = 0; g < 16; ++g) {
            float4 t = *(const float4*)&row[g*4];
            v[4*g]=t.x; v[4*g+1]=t.y; v[4*g+2]=t.z; v[4*g+3]=t.w;
            ss += t.x*t.x + t.y*t.y + t.z*t.z + t.w*t.w;
        }
        float inv = 1.0f / (sqrtf(ss) + 1e-6f);
        #pragma unroll
        for (int i = 0; i < 64; ++i) dir[i] += v[i] * inv;
    }
    #pragma unroll
    for (int i = 0; i < 64; ++i)
        for (int off = 32; off; off >>= 1) dir[i] += __shfl_xor(dir[i], off);

    __shared__ float sdir[4][64];
    int lane = tid & 63, wid = tid >> 6;
    if (lane == 0) {
        #pragma unroll
        for (int i = 0; i < 64; ++i) sdir[wid][i] = dir[i];
    }
    __syncthreads();
    if (tid < 64) {
        float s = sdir[0][tid] + sdir[1][tid] + sdir[2][tid] + sdir[3][tid];
        ws[WS_MD + (size_t)bh*DD + tid] = s * (1.0f / (float)NCAND);
    }
}

__global__ __launch_bounds__(256) void scores_k(const float* __restrict__ past_k,
                                                float* __restrict__ ws)
{
    __shared__ float md[64];
    __shared__ float sred[4];
    int bh = blockIdx.x, tid = threadIdx.x;
    if (tid < 64) md[tid] = ws[WS_MD + (size_t)bh*DD + tid];
    __syncthreads();
    const float* kpast = past_k + (size_t)bh * NPAST * DD;
    const float* knew  = ws + WS_KF + (size_t)bh * NN * DD;
    float ssum = 0.f;
    for (int j = tid; j < NCAND; j += 256) {
        int pos = NANCH + j;
        const float* row = (pos < NPAST) ? (kpast + (size_t)pos * DD)
                                         : (knew + (size_t)(pos - NPAST) * DD);
        float ss = 0.f, dp = 0.f;
        #pragma unroll
        for (int g = 0; g < 16; ++g) {
            float4 t = *(const float4*)&row[g*4];
            ss += t.x*t.x + t.y*t.y + t.z*t.z + t.w*t.w;
            dp += t.x*md[4*g] + t.y*md[4*g+1] + t.z*md[4*g+2] + t.w*md[4*g+3];
        }
        float sc = dp / (sqrtf(ss) + 1e-6f);
        ws[WS_SC + (size_t)bh*NCAND + j] = sc;
        ssum += sc;
    }
    for (int off = 32; off; off >>= 1) ssum += __shfl_xor(ssum, off);
    int lane = tid & 63, wid = tid >> 6;
    if (lane == 0) sred[wid] = ssum;
    __syncthreads();
    if (tid == 0) ws[WS_BS + bh] = sred[0] + sred[1] + sred[2] + sred[3];
}

__global__ void avg_k(const float* __restrict__ ws, float* __restrict__ dout)
{
    int tid = threadIdx.x;
    float v = (tid < BH) ? ws[WS_BS + tid] : 0.f;
    for (int off = 32; off; off >>= 1) v += __shfl_xor(v, off);
    if (tid == 0) dout[AVG_OFF] = v * (1.0f / ((float)BH * (float)NCAND));
}

// ============================================================
// exact radix-select + stable index-ordered compaction
// ============================================================
__global__ __launch_bounds__(1024) void topk_k(float* __restrict__ ws, int* __restrict__ sel)
{
    __shared__ unsigned keys[NCAND];
    __shared__ int red[16];
    __shared__ int red2[16];
    __shared__ int bcast;
    int bh = blockIdx.x, tid = threadIdx.x;
    int lane = tid & 63, wid = tid >> 6;

    for (int j = tid; j < NCAND; j += 1024) {
        unsigned u = __float_as_uint(ws[WS_SC + (size_t)bh*NCAND + j]);
        u ^= (u & 0x80000000u) ? 0xFFFFFFFFu : 0x80000000u;
        keys[j] = u;
    }
    __syncthreads();

    unsigned prefix = 0; int rem = NKEEP;
    for (int bit = 31; bit >= 0; --bit) {
        unsigned bm = 1u << bit;
        unsigned hm = ~((bm << 1) - 1u);
        int cnt = 0;
        for (int j = tid; j < NCAND; j += 1024) {
            unsigned k = keys[j];
            cnt += (int)(((k & hm) == prefix) & ((k & bm) == 0u));
        }
        for (int off = 32; off; off >>= 1) cnt += __shfl_xor(cnt, off);
        if (lane == 0) red[wid] = cnt;
        __syncthreads();
        if (tid == 0) { int c = 0; for (int i = 0; i < 16; ++i) c += red[i]; bcast = c; }
        __syncthreads();
        int c0 = bcast;
        if (rem <= c0) {} else { rem -= c0; prefix |= bm; }
        __syncthreads();
    }
    unsigned T = prefix;

    {
        int cnt = 0;
        for (int j = tid; j < NCAND; j += 1024) cnt += (int)(keys[j] < T);
        for (int off = 32; off; off >>= 1) cnt += __shfl_xor(cnt, off);
        if (lane == 0) red[wid] = cnt;
        __syncthreads();
        if (tid == 0) { int c = 0; for (int i = 0; i < 16; ++i) c += red[i]; bcast = c; }
        __syncthreads();
    }
    int c_less = bcast;
    int ttie = NKEEP - c_less;

    int base = tid * 8;
    unsigned kv[8]; int lcnt = 0, ecnt = 0;
    #pragma unroll
    for (int i = 0; i < 8; ++i) {
        kv[i] = keys[base + i];
        lcnt += (int)(kv[i] < T);
        ecnt += (int)(kv[i] == T);
    }
    int li = lcnt, ei = ecnt;
    for (int off = 1; off < 64; off <<= 1) {
        int tl = __shfl_up(li, off);
        int te = __shfl_up(ei, off);
        if (lane >= off) { li += tl; ei += te; }
    }
    __syncthreads();
    if (lane == 63) { red[wid] = li; red2[wid] = ei; }
    __syncthreads();
    int lb = 0, eb = 0;
    for (int w = 0; w < wid; ++w) { lb += red[w]; eb += red2[w]; }
    lb += li - lcnt; eb += ei - ecnt;
    #pragma unroll
    for (int i = 0; i < 8; ++i) {
        bool less = kv[i] < T, eq = kv[i] == T;
        if (less || (eq && eb < ttie)) {
            int pos = lb + (eb < ttie ? eb : ttie);
            sel[(size_t)bh*NKEEP + pos] = base + i;
        }
        lb += (int)less; eb += (int)eq;
    }
}

// ============================================================
// gather k_new / v_new (fp32, exact) into d_out
// ============================================================
__global__ __launch_bounds__(256) void gather_k(const float* __restrict__ past_k,
                                                const float* __restrict__ past_v,
                                                const float* __restrict__ ws,
                                                const int* __restrict__ sel,
                                                float* __restrict__ dout)
{
    int gid = blockIdx.x * 256 + threadIdx.x;
    int row = gid >> 4, lane = gid & 15;
    int bh = row >> 12, r = row & 4095;
    int pos = (r < NANCH) ? r : (NANCH + sel[(size_t)bh*NKEEP + (r - NANCH)]);
    const float *kr, *vr;
    if (pos < NPAST) {
        kr = past_k + ((size_t)bh*NPAST + pos) * DD;
        vr = past_v + ((size_t)bh*NPAST + pos) * DD;
    } else {
        kr = ws + WS_KF + ((size_t)bh*NN + (pos - NPAST)) * DD;
        vr = ws + WS_VF + ((size_t)bh*NN + (pos - NPAST)) * DD;
    }
    float4 kq = *(const float4*)&kr[lane*4];
    float4 vq = *(const float4*)&vr[lane*4];
    *(float4*)&dout[KNEW_OFF + ((size_t)bh*CBUD + r)*DD + lane*4] = kq;
    *(float4*)&dout[VNEW_OFF + ((size_t)bh*CBUD + r)*DD + lane*4] = vq;
}

// ============================================================
// V^T bf16: vt[bh][d][key] from v_new fp32
// ============================================================
__global__ __launch_bounds__(256) void vtrans_k(const float* __restrict__ dout,
                                                unsigned short* __restrict__ vt)
{
    __shared__ unsigned short S[64][65];
    int bh = blockIdx.x >> 6, kt = blockIdx.x & 63;
    int c0 = kt * 64;
    int tid = threadIdx.x;
    int r = tid >> 2, c4 = (tid & 3) * 16;
    const float* src = dout + VNEW_OFF + ((size_t)bh*CBUD + c0 + r)*DD + c4;
    #pragma unroll
    for (int i = 0; i < 4; ++i) {
        float4 f = *(const float4*)&src[i*4];
        S[r][c4 + i*4 + 0] = f2bf(f.x);
        S[r][c4 + i*4 + 1] = f2bf(f.y);
        S[r][c4 + i*4 + 2] = f2bf(f.z);
        S[r][c4 + i*4 + 3] = f2bf(f.w);
    }
    __syncthreads();
    int d = r, k4 = c4;
    uint4 u0, u1;
    u0.x = (unsigned)S[k4+0][d] | ((unsigned)S[k4+1][d] << 16);
    u0.y = (unsigned)S[k4+2][d] | ((unsigned)S[k4+3][d] << 16);
    u0.z = (unsigned)S[k4+4][d] | ((unsigned)S[k4+5][d] << 16);
    u0.w = (unsigned)S[k4+6][d] | ((unsigned)S[k4+7][d] << 16);
    u1.x = (unsigned)S[k4+8][d] | ((unsigned)S[k4+9][d] << 16);
    u1.y = (unsigned)S[k4+10][d] | ((unsigned)S[k4+11][d] << 16);
    u1.z = (unsigned)S[k4+12][d] | ((unsigned)S[k4+13][d] << 16);
    u1.w = (unsigned)S[k4+14][d] | ((unsigned)S[k4+15][d] << 16);
    unsigned short* dst = vt + ((size_t)bh*DD + d)*CBUD + c0 + k4;
    *(uint4*)&dst[0] = u0;
    *(uint4*)&dst[8] = u1;
}

// ============================================================
// MFMA flash attention, swapped QK^T (S^T), lane-local softmax,
// defer-max, dbuf KV staging (1 barrier/tile), bf16 O to tiled ot.
// ============================================================
__global__ __launch_bounds__(256) void attn_mfma(const unsigned short* __restrict__ qb,
                                                 const float* __restrict__ dout,
                                                 const unsigned short* __restrict__ vt,
                                                 unsigned short* __restrict__ ot)
{
    __shared__ char kls[2][8192];
    __shared__ char vls[2][8192];
    __shared__ char pls[4][2048];

    int orig = blockIdx.x;
    int bid = (orig & 7) * 64 + (orig >> 3);
    int bh = bid >> 4, qt = bid & 15;
    int b = bh >> 4, h = bh & 15;
    int tid = threadIdx.x;
    int w = tid >> 6, lane = tid & 63;
    int g = lane >> 4, r16 = lane & 15;
    int q0 = qt * 64 + w * 16;

    const unsigned short* qrow = qb + ((size_t)bh*NN + q0 + r16) * DD;
    short8 qa0 = *(const short8*)&qrow[8*g];
    short8 qa1 = *(const short8*)&qrow[32 + 8*g];

    const float* kf = dout + KNEW_OFF + (size_t)bh * CBUD * DD;
    const unsigned short* vtb = vt + (size_t)bh * DD * CBUD;
    char* plw = pls[w];
    int psw = (r16 & 7) << 4;

    int srow = tid >> 2;
    int scol = (tid & 3) * 32;
    int ssw = (srow & 7) << 4;
    int sd0 = ((srow * 128 + scol)      ^ ssw);
    int sd1 = ((srow * 128 + scol + 16) ^ ssw);

    f32x4 accd[4];
    #pragma unroll
    for (int dt = 0; dt < 4; ++dt) accd[dt] = 0.f;
    float m = -3.0e38f, l = 0.f;

    {
        const float* ks = kf + (size_t)srow * DD + (scol >> 1);
        float4 f0 = *(const float4*)ks;
        float4 f1 = *(const float4*)(ks + 4);
        float4 f2 = *(const float4*)(ks + 8);
        float4 f3 = *(const float4*)(ks + 12);
        uint4 ku0, ku1;
        ku0.x = cvtpk(f0.x,f0.y); ku0.y = cvtpk(f0.z,f0.w);
        ku0.z = cvtpk(f1.x,f1.y); ku0.w = cvtpk(f1.z,f1.w);
        ku1.x = cvtpk(f2.x,f2.y); ku1.y = cvtpk(f2.z,f2.w);
        ku1.z = cvtpk(f3.x,f3.y); ku1.w = cvtpk(f3.z,f3.w);
        const unsigned short* vs = vtb + (size_t)srow * CBUD + (scol >> 1);
        uint4 vu0 = *(const uint4*)vs;
        uint4 vu1 = *(const uint4*)(vs + 8);
        *(uint4*)&kls[0][sd0] = ku0; *(uint4*)&kls[0][sd1] = ku1;
        *(uint4*)&vls[0][sd0] = vu0; *(uint4*)&vls[0][sd1] = vu1;
    }
    __syncthreads();

    int cur = 0;
    for (int t = 0; t < 64; ++t) {
        float4 f0, f1, f2, f3; uint4 vu0, vu1;
        bool more = (t + 1 < 64);
        if (more) {
            const float* ks = kf + (size_t)(t+1) * 64 * DD + (size_t)srow * DD + (scol >> 1);
            f0 = *(const float4*)ks;
            f1 = *(const float4*)(ks + 4);
            f2 = *(const float4*)(ks + 8);
            f3 = *(const float4*)(ks + 12);
            const unsigned short* vs = vtb + (size_t)srow * CBUD + (size_t)(t+1) * 64 + (scol >> 1);
            vu0 = *(const uint4*)vs;
            vu1 = *(const uint4*)(vs + 8);
        }

        const char* kb = kls[cur];
        f32x4 sacc[4];
        #pragma unroll
        for (int t4 = 0; t4 < 4; ++t4) sacc[t4] = 0.f;
        #pragma unroll
        for (int t4 = 0; t4 < 4; ++t4) {
            int row = 16*t4 + r16;
            int sw = (r16 & 7) << 4;
            short8 ka0 = *(const short8*)(kb + ((row*128 + g*16) ^ sw));
            short8 ka1 = *(const short8*)(kb + ((row*128 + 64 + g*16) ^ sw));
            sacc[t4] = __builtin_amdgcn_mfma_f32_16x16x32_bf16(ka0, qa0, sacc[t4], 0, 0, 0);
            sacc[t4] = __builtin_amdgcn_mfma_f32_16x16x32_bf16(ka1, qa1, sacc[t4], 0, 0, 0);
        }

        float sv[4][4];
        float smax = -3.0e38f;
        #pragma unroll
        for (int t4 = 0; t4 < 4; ++t4)
            #pragma unroll
            for (int rr = 0; rr < 4; ++rr) {
                sv[t4][rr] = sacc[t4][rr] * 0.125f;
                smax = fmaxf(smax, sv[t4][rr]);
            }
        smax = fmaxf(smax, __shfl_xor(smax, 16));
        smax = fmaxf(smax, __shfl_xor(smax, 32));

        if (!__all(smax <= m + 8.0f)) {
            float mnew = fmaxf(m, smax);
            float rs = __expf(m - mnew);
            l *= rs;
            m = mnew;
            float rq0 = __shfl(rs, 20*g + 0);
            float rq1 = __shfl(rs, 20*g + 1);
            float rq2 = __shfl(rs, 20*g + 2);
            float rq3 = __shfl(rs, 20*g + 3);
            #pragma unroll
            for (int dt = 0; dt < 4; ++dt) {
                accd[dt][0] *= rq0; accd[dt][1] *= rq1;
                accd[dt][2] *= rq2; accd[dt][3] *= rq3;
            }
        }

        float ps = 0.f;
        float p[4][4];
        #pragma unroll
        for (int t4 = 0; t4 < 4; ++t4)
            #pragma unroll
            for (int rr = 0; rr < 4; ++rr) {
                p[t4][rr] = __expf(sv[t4][rr] - m);
                ps += p[t4][rr];
            }
        #pragma unroll
        for (int t4 = 0; t4 < 4; ++t4) {
            unsigned u0 = cvtpk(p[t4][0], p[t4][1]);
            unsigned u1 = cvtpk(p[t4][2], p[t4][3]);
            int cb = (16*t4 + 4*g) * 2;
            *(unsigned*)&plw[(r16*128 + cb)     ^ psw] = u0;
            *(unsigned*)&plw[(r16*128 + cb + 4) ^ psw] = u1;
        }
        ps += __shfl_xor(ps, 16);
        ps += __shfl_xor(ps, 32);
        l += ps;

        short8 pa0 = *(const short8*)&plw[(r16*128 + 16*g)      ^ psw];
        short8 pa1 = *(const short8*)&plw[(r16*128 + 64 + 16*g) ^ psw];
        const char* vb = vls[cur];
        #pragma unroll
        for (int dt = 0; dt < 4; ++dt) {
            int row = dt*16 + r16;
            int sw = (r16 & 7) << 4;
            short8 vb0 = *(const short8*)(vb + ((row*128 + g*16) ^ sw));
            short8 vb1 = *(const short8*)(vb + ((row*128 + 64 + g*16) ^ sw));
            accd[dt] = __builtin_amdgcn_mfma_f32_16x16x32_bf16(pa0, vb0, accd[dt], 0, 0, 0);
            accd[dt] = __builtin_amdgcn_mfma_f32_16x16x32_bf16(pa1, vb1, accd[dt], 0, 0, 0);
        }

        if (more) {
            uint4 ku0, ku1;
            ku0.x = cvtpk(f0.x,f0.y); ku0.y = cvtpk(f0.z,f0.w);
            ku0.z = cvtpk(f1.x,f1.y); ku0.w = cvtpk(f1.z,f1.w);
            ku1.x = cvtpk(f2.x,f2.y); ku1.y = cvtpk(f2.z,f2.w);
            ku1.z = cvtpk(f3.x,f3.y); ku1.w = cvtpk(f3.z,f3.w);
            *(uint4*)&kls[cur^1][sd0] = ku0; *(uint4*)&kls[cur^1][sd1] = ku1;
            *(uint4*)&vls[cur^1][sd0] = vu0; *(uint4*)&vls[cur^1][sd1] = vu1;
        }
        __syncthreads();
        cur ^= 1;
    }

    float ivl = 1.0f / l;
    float iq0 = __shfl(ivl, 20*g + 0);
    float iq1 = __shfl(ivl, 20*g + 1);
    float iq2 = __shfl(ivl, 20*g + 2);
    float iq3 = __shfl(ivl, 20*g + 3);
    float iq[4] = {iq0, iq1, iq2, iq3};
    #pragma unroll
    for (int dt = 0; dt < 4; ++dt) {
        #pragma unroll
        for (int rr = 0; rr < 4; ++rr) {
            int q = q0 + 4*g + rr;
            int mrow = b*1024 + q;
            int d = dt*16 + r16;
            size_t tile = (size_t)(mrow >> 7) * 16 + h;
            int inner = ((mrow & 127)*128 + d*2) ^ ((mrow & 7) << 4);
            *(unsigned short*)((char*)ot + tile*TILEB + inner) = f2bf(accd[dt][rr] * iq[rr]);
        }
    }
}

// ============================================================
extern "C" void kernel_launch(void* const* d_in, const int* in_sizes, int n_in,
                              void* d_out, int out_size, void* d_ws, size_t ws_size,
                              hipStream_t stream)
{
    (void)in_sizes; (void)n_in; (void)out_size; (void)ws_size;
    const float* x      = (const float*)d_in[0];
    const float* past_k = (const float*)d_in[1];
    const float* past_v = (const float*)d_in[2];
    const float* qkv_w  = (const float*)d_in[3];
    const float* qkv_b  = (const float*)d_in[4];
    const float* proj_w = (const float*)d_in[5];
    const float* proj_b = (const float*)d_in[6];
    float* out = (float*)d_out;
    float* ws  = (float*)d_ws;
    int*   sel = (int*)(ws + WS_SEL);
    unsigned short* xt   = (unsigned short*)(ws + WS_XT);
    unsigned short* wqvt = (unsigned short*)(ws + WS_WQVT);
    unsigned short* wpt  = (unsigned short*)(ws + WS_WPT);
    unsigned short* qbp  = (unsigned short*)(ws + WS_QB);
    unsigned short* vtp  = (unsigned short*)(ws + WS_VT);
    unsigned short* otp  = (unsigned short*)(ws + WS_OT);

    conv_tile<<<1024, 256, 0, stream>>>(x, xt);
    conv_wqv<<<1024, 256, 0, stream>>>(qkv_w, wqvt);
    kf_gemm<<<dim3(16, 32), 256, 0, stream>>>(x, qkv_w, qkv_b, ws);
    mfma_gemm<0><<<dim3(16, 16), 256, 0, stream>>>(xt, wqvt, qkv_b, ws);
    meandir_k<<<32, 256, 0, stream>>>(past_k, ws);
    scores_k<<<32, 256, 0, stream>>>(past_k, ws);
    avg_k<<<1, 64, 0, stream>>>(ws, out);
    topk_k<<<32, 1024, 0, stream>>>(ws, sel);
    gather_k<<<8192, 256, 0, stream>>>(past_k, past_v, ws, sel, out);
    vtrans_k<<<2048, 256, 0, stream>>>(out, vtp);
    conv_tile<<<512, 256, 0, stream>>>(proj_w, wpt);
    attn_mfma<<<512, 256, 0, stream>>>(qbp, out, vtp, otp);
    mfma_gemm<1><<<dim3(8, 16), 256, 0, stream>>>(otp, wpt, proj_b, out);
}

// Round 6
// 303.412 us; speedup vs baseline: 7.2898x; 1.3560x over previous
//
#include <hip/hip_runtime.h>
#include <hip/hip_bf16.h>
#include <math.h>

// ---- problem constants ----
#define BB 2
#define HH 16
#define NN 1024
#define CC 1024
#define DD 64
#define NPAST 8192
#define NANCH 1024
#define CBUD 4096
#define NKEEP 3072
#define NCAND 8192
#define BH 32

// tiled bf16 layout: K-chunk tile = 128 rows x 64 k x 2B = 16384 bytes
#define TILEB 16384

// ---- d_out layout (floats) ----
#define OUT_SZ   (BB*NN*CC)
#define KNEW_OFF ((size_t)OUT_SZ)
#define KNEW_SZ  ((size_t)BH*CBUD*DD)
#define VNEW_OFF (KNEW_OFF + KNEW_SZ)
#define AVG_OFF  (VNEW_OFF + KNEW_SZ)

// ---- workspace layout (float offsets), with overlays ----
#define WS_KF   ((size_t)0)            // 2097152 f
#define WS_VF   ((size_t)2097152)     // 2097152 f
#define WS_VT   ((size_t)0)            // bf16 V^T overlay (after gather)
#define WS_XT   ((size_t)4194304)     // x tiled bf16: 1048576 f
#define WS_OT   ((size_t)4194304)     // o tiled bf16 (overlay XT)
#define WS_WQVT ((size_t)5242880)     // w(Q,V) tiled bf16: 1048576 f
#define WS_WPT  ((size_t)5242880)     // proj_w tiled bf16 (overlay)
#define WS_QB   ((size_t)6291456)     // q bf16: 1048576 f
#define WS_MD   ((size_t)7340032)     // 2048 f
#define WS_SC   ((size_t)7342080)     // 262144 f
#define WS_BS   ((size_t)7604224)     // 64 f
#define WS_SEL  ((size_t)7604288)     // 98304 ints -> ends 7702592
#define WS_MDP  ((size_t)7702592)     // mean_dir partials [32][8][64] = 16384 f
#define WS_BSP  ((size_t)7718976)     // score-sum partials [32][8] = 256 f
// end = 7719232 floats = 30.9 MB

typedef __attribute__((ext_vector_type(8))) short short8;
typedef __attribute__((ext_vector_type(4))) float f32x4;

typedef unsigned int __attribute__((address_space(3))) lds_uint;
typedef unsigned int __attribute__((address_space(1))) glb_uint;

__device__ __forceinline__ void gload16(const void* g, void* l) {
    __builtin_amdgcn_global_load_lds((const glb_uint*)g, (lds_uint*)l, 16, 0, 0);
}

__device__ inline unsigned short f2bf(float f) {
    unsigned u = __float_as_uint(f);
    unsigned r = (u + 0x7FFFu + ((u >> 16) & 1u)) >> 16;
    return (unsigned short)r;
}
__device__ inline unsigned cvtpk(float a, float b) {
    __hip_bfloat162 h = __float22bfloat162_rn(make_float2(a, b));
    return *reinterpret_cast<unsigned*>(&h);
}
__device__ __forceinline__ float fexp2(float x) {
#if __has_builtin(__builtin_amdgcn_exp2f)
    return __builtin_amdgcn_exp2f(x);
#else
    return exp2f(x);
#endif
}

// ============================================================
// converters: fp32 row-major -> tiled swizzled bf16
// tile = (row>>7)*16 + (k>>6); inner = ((row&127)*128 + (k&63)*2) ^ ((row&7)<<4)
// ============================================================
__global__ __launch_bounds__(256) void conv_tile(const float* __restrict__ src,
                                                 unsigned short* __restrict__ dst)
{
    int gid = blockIdx.x * 256 + threadIdx.x;
    int r = gid >> 7, k0 = (gid & 127) * 8;
    float4 a = *(const float4*)&src[(size_t)r * 1024 + k0];
    float4 b = *(const float4*)&src[(size_t)r * 1024 + k0 + 4];
    uint4 u;
    u.x = cvtpk(a.x, a.y); u.y = cvtpk(a.z, a.w);
    u.z = cvtpk(b.x, b.y); u.w = cvtpk(b.z, b.w);
    size_t tile = (size_t)(r >> 7) * 16 + (k0 >> 6);
    int inner = (((r & 127) * 128 + (k0 & 63) * 2)) ^ ((r & 7) << 4);
    *(uint4*)((char*)dst + tile * TILEB + inner) = u;
}

// Q/V rows of qkv_w: n<1024 -> row n (Q), n>=1024 -> row n+1024 (V)
__global__ __launch_bounds__(256) void conv_wqv(const float* __restrict__ src,
                                                unsigned short* __restrict__ dst)
{
    int gid = blockIdx.x * 256 + threadIdx.x;
    int n = gid >> 7, k0 = (gid & 127) * 8;
    int srow = (n < 1024) ? n : n + 1024;
    float4 a = *(const float4*)&src[(size_t)srow * 1024 + k0];
    float4 b = *(const float4*)&src[(size_t)srow * 1024 + k0 + 4];
    uint4 u;
    u.x = cvtpk(a.x, a.y); u.y = cvtpk(a.z, a.w);
    u.z = cvtpk(b.x, b.y); u.w = cvtpk(b.z, b.w);
    size_t tile = (size_t)(n >> 7) * 16 + (k0 >> 6);
    int inner = (((n & 127) * 128 + (k0 & 63) * 2)) ^ ((n & 7) << 4);
    *(uint4*)((char*)dst + tile * TILEB + inner) = u;
}

// ============================================================
// fp32 GEMM for K-third (precision-critical ranking path).
// Register-prefetched staging; accumulation order identical.
// ============================================================
__global__ __launch_bounds__(256) void kf_gemm(const float* __restrict__ x,
                                               const float* __restrict__ w,
                                               const float* __restrict__ bias,
                                               float* __restrict__ ws)
{
    __shared__ float As[16][68];
    __shared__ float Bs[16][68];
    int tid = threadIdx.x;
    int m0 = blockIdx.y * 64;
    int n0 = blockIdx.x * 64;
    int tx = tid & 15, ty = tid >> 4;
    int lr = tid >> 2;
    int lk = (tid & 3) * 4;
    float acc[4][4] = {{0.f}};

    // prefetch k0=0
    float4 a = *(const float4*)&x[(size_t)(m0 + lr) * CC + lk];
    float4 b = *(const float4*)&w[(size_t)(1024 + n0 + lr) * CC + lk];

    for (int k0 = 0; k0 < CC; k0 += 16) {
        __syncthreads();
        As[lk+0][lr] = a.x; As[lk+1][lr] = a.y; As[lk+2][lr] = a.z; As[lk+3][lr] = a.w;
        Bs[lk+0][lr] = b.x; Bs[lk+1][lr] = b.y; Bs[lk+2][lr] = b.z; Bs[lk+3][lr] = b.w;
        __syncthreads();
        if (k0 + 16 < CC) {
            a = *(const float4*)&x[(size_t)(m0 + lr) * CC + k0 + 16 + lk];
            b = *(const float4*)&w[(size_t)(1024 + n0 + lr) * CC + k0 + 16 + lk];
        }
        float tacc[4][4] = {{0.f}};
        #pragma unroll
        for (int kk = 0; kk < 16; ++kk) {
            float4 a4 = *(const float4*)&As[kk][ty*4];
            float4 b4 = *(const float4*)&Bs[kk][tx*4];
            float av[4] = {a4.x, a4.y, a4.z, a4.w};
            float bv[4] = {b4.x, b4.y, b4.z, b4.w};
            #pragma unroll
            for (int i = 0; i < 4; ++i)
                #pragma unroll
                for (int j = 0; j < 4; ++j)
                    tacc[i][j] += av[i] * bv[j];
        }
        #pragma unroll
        for (int i = 0; i < 4; ++i)
            #pragma unroll
            for (int j = 0; j < 4; ++j)
                acc[i][j] += tacc[i][j];
    }

    int cn0 = n0 + tx * 4;
    int h = cn0 >> 6, dd0 = cn0 & 63;
    float4 b4 = *(const float4*)&bias[1024 + cn0];
    float* kf = ws + WS_KF;
    #pragma unroll
    for (int i = 0; i < 4; ++i) {
        int m = m0 + ty * 4 + i;
        int b2 = m >> 10, n = m & 1023;
        float4 t;
        t.x = acc[i][0] + b4.x; t.y = acc[i][1] + b4.y;
        t.z = acc[i][2] + b4.z; t.w = acc[i][3] + b4.w;
        *(float4*)&kf[(((size_t)b2*HH + h)*NN + n)*DD + dd0] = t;
    }
}

// ============================================================
// bf16 MFMA GEMM, 128x128 tile, BK=64, pre-tiled swizzled inputs,
// global_load_lds staging, stage-ahead + 1 barrier/step.
// MODE 0: QV epilogue (Q->bf16 qb, V->fp32 vf). MODE 1: proj -> dout.
// ============================================================
template<int MODE>
__global__ __launch_bounds__(256) void mfma_gemm(const unsigned short* __restrict__ At,
                                                 const unsigned short* __restrict__ Bt,
                                                 const float* __restrict__ bias,
                                                 float* __restrict__ outp)
{
    __shared__ char lds[131072];
    int tid = threadIdx.x;
    int w = tid >> 6, lane = tid & 63;
    int g = lane >> 4, r16 = lane & 15;
    int wr = w >> 1, wc = w & 1;
    int bm = blockIdx.y, bn = blockIdx.x;
    const int KB = 16;

    f32x4 acc[4][4];
    #pragma unroll
    for (int i = 0; i < 4; ++i)
        #pragma unroll
        for (int j = 0; j < 4; ++j) acc[i][j] = 0.f;

    const char* Abase = (const char*)At + (size_t)bm * KB * TILEB;
    const char* Bbase = (const char*)Bt + (size_t)bn * KB * TILEB;

    #pragma unroll
    for (int i = 0; i < 4; ++i) {
        gload16(Abase + (size_t)w*4096 + i*1024 + lane*16, lds + w*4096 + i*1024);
        gload16(Bbase + (size_t)w*4096 + i*1024 + lane*16, lds + TILEB + w*4096 + i*1024);
    }
    asm volatile("s_waitcnt vmcnt(0)" ::: "memory");
    __syncthreads();

    int cur = 0;
    for (int kb = 0; kb < KB; ++kb) {
        char* Acur = lds + cur * (2*TILEB);
        char* Bcur = Acur + TILEB;
        if (kb + 1 < KB) {
            char* Anxt = lds + (cur ^ 1) * (2*TILEB);
            char* Bnxt = Anxt + TILEB;
            const char* an = Abase + (size_t)(kb+1)*TILEB + w*4096;
            const char* bsrc = Bbase + (size_t)(kb+1)*TILEB + w*4096;
            #pragma unroll
            for (int i = 0; i < 4; ++i) {
                gload16(an + i*1024 + lane*16, Anxt + w*4096 + i*1024);
                gload16(bsrc + i*1024 + lane*16, Bnxt + w*4096 + i*1024);
            }
        }
        short8 a0[4], a1[4], b0[4], b1[4];
        #pragma unroll
        for (int mi = 0; mi < 4; ++mi) {
            int row = wr*64 + mi*16 + r16;
            int sw = (row & 7) << 4;
            a0[mi] = *(const short8*)(Acur + ((row*128 + g*16) ^ sw));
            a1[mi] = *(const short8*)(Acur + ((row*128 + 64 + g*16) ^ sw));
        }
        #pragma unroll
        for (int ni = 0; ni < 4; ++ni) {
            int row = wc*64 + ni*16 + r16;
            int sw = (row & 7) << 4;
            b0[ni] = *(const short8*)(Bcur + ((row*128 + g*16) ^ sw));
            b1[ni] = *(const short8*)(Bcur + ((row*128 + 64 + g*16) ^ sw));
        }
        __builtin_amdgcn_s_setprio(1);
        #pragma unroll
        for (int mi = 0; mi < 4; ++mi)
            #pragma unroll
            for (int ni = 0; ni < 4; ++ni) {
                acc[mi][ni] = __builtin_amdgcn_mfma_f32_16x16x32_bf16(a0[mi], b0[ni], acc[mi][ni], 0, 0, 0);
                acc[mi][ni] = __builtin_amdgcn_mfma_f32_16x16x32_bf16(a1[mi], b1[ni], acc[mi][ni], 0, 0, 0);
            }
        __builtin_amdgcn_s_setprio(0);
        asm volatile("s_waitcnt vmcnt(0)" ::: "memory");
        __syncthreads();
        cur ^= 1;
    }

    int nq = bn*128 + wc*64;
    float bv[4];
    #pragma unroll
    for (int ni = 0; ni < 4; ++ni) {
        int n = nq + ni*16 + r16;
        bv[ni] = (MODE == 0) ? bias[(n < 1024) ? n : (n + 1024)] : bias[n];
    }
    #pragma unroll
    for (int mi = 0; mi < 4; ++mi) {
        #pragma unroll
        for (int rr = 0; rr < 4; ++rr) {
            int ml = wr*64 + mi*16 + 4*g + rr;
            int mg = bm*128 + ml;
            int bb = mg >> 10, tok = mg & 1023;
            #pragma unroll
            for (int ni = 0; ni < 4; ++ni) {
                int n = nq + ni*16 + r16;
                float v = acc[mi][ni][rr] + bv[ni];
                if (MODE == 0) {
                    if (n < 1024) {
                        unsigned short* qb = (unsigned short*)(outp + WS_QB);
                        int hh = n >> 6, d = n & 63;
                        qb[(((size_t)bb*16 + hh)*1024 + tok)*64 + d] = f2bf(v);
                    } else {
                        float* vf = outp + WS_VF;
                        int hh = (n - 1024) >> 6, d = n & 63;
                        vf[(((size_t)bb*16 + hh)*1024 + tok)*64 + d] = v;
                    }
                } else {
                    outp[(size_t)mg*1024 + n] = v;
                }
            }
        }
    }
}

// ============================================================
// mean_dir partials: grid (32 bh, 8 seg) x 256 thr
// ============================================================
__global__ __launch_bounds__(256) void meandir_part(const float* __restrict__ past_k,
                                                    float* __restrict__ ws)
{
    int bh = blockIdx.x, seg = blockIdx.y, tid = threadIdx.x;
    const float* kpast = past_k + (size_t)bh * NPAST * DD;
    const float* knew  = ws + WS_KF + (size_t)bh * NN * DD;
    float dir[64];
    #pragma unroll
    for (int i = 0; i < 64; ++i) dir[i] = 0.f;

    int j0 = seg * 1024;
    for (int jj = tid; jj < 1024; jj += 256) {
        int pos = NANCH + j0 + jj;
        const float* row = (pos < NPAST) ? (kpast + (size_t)pos * DD)
                                         : (knew + (size_t)(pos - NPAST) * DD);
        float v[64]; float ss = 0.f;
        #pragma unroll
        for (int g = 0; g < 16; ++g) {
            float4 t = *(const float4*)&row[g*4];
            v[4*g]=t.x; v[4*g+1]=t.y; v[4*g+2]=t.z; v[4*g+3]=t.w;
            ss += t.x*t.x + t.y*t.y + t.z*t.z + t.w*t.w;
        }
        float inv = 1.0f / (sqrtf(ss) + 1e-6f);
        #pragma unroll
        for (int i = 0; i < 64; ++i) dir[i] += v[i] * inv;
    }
    #pragma unroll
    for (int i = 0; i < 64; ++i)
        for (int off = 32; off; off >>= 1) dir[i] += __shfl_xor(dir[i], off);

    __shared__ float sdir[4][64];
    int lane = tid & 63, wid = tid >> 6;
    if (lane == 0) {
        #pragma unroll
        for (int i = 0; i < 64; ++i) sdir[wid][i] = dir[i];
    }
    __syncthreads();
    if (tid < 64) {
        float s = sdir[0][tid] + sdir[1][tid] + sdir[2][tid] + sdir[3][tid];
        ws[WS_MDP + ((size_t)bh*8 + seg)*DD + tid] = s;
    }
}

__global__ void meandir_red(float* __restrict__ ws)
{
    int bh = blockIdx.x, tid = threadIdx.x;   // 64 thr
    float s = 0.f;
    #pragma unroll
    for (int seg = 0; seg < 8; ++seg)
        s += ws[WS_MDP + ((size_t)bh*8 + seg)*DD + tid];
    ws[WS_MD + (size_t)bh*DD + tid] = s * (1.0f / (float)NCAND);
}

// ============================================================
// scores partials: grid (32 bh, 8 seg) x 256 thr
// ============================================================
__global__ __launch_bounds__(256) void scores_part(const float* __restrict__ past_k,
                                                   float* __restrict__ ws)
{
    __shared__ float md[64];
    __shared__ float sred[4];
    int bh = blockIdx.x, seg = blockIdx.y, tid = threadIdx.x;
    if (tid < 64) md[tid] = ws[WS_MD + (size_t)bh*DD + tid];
    __syncthreads();
    const float* kpast = past_k + (size_t)bh * NPAST * DD;
    const float* knew  = ws + WS_KF + (size_t)bh * NN * DD;
    float ssum = 0.f;
    int j0 = seg * 1024;
    for (int jj = tid; jj < 1024; jj += 256) {
        int j = j0 + jj;
        int pos = NANCH + j;
        const float* row = (pos < NPAST) ? (kpast + (size_t)pos * DD)
                                         : (knew + (size_t)(pos - NPAST) * DD);
        float ss = 0.f, dp = 0.f;
        #pragma unroll
        for (int g = 0; g < 16; ++g) {
            float4 t = *(const float4*)&row[g*4];
            ss += t.x*t.x + t.y*t.y + t.z*t.z + t.w*t.w;
            dp += t.x*md[4*g] + t.y*md[4*g+1] + t.z*md[4*g+2] + t.w*md[4*g+3];
        }
        float sc = dp / (sqrtf(ss) + 1e-6f);
        ws[WS_SC + (size_t)bh*NCAND + j] = sc;
        ssum += sc;
    }
    for (int off = 32; off; off >>= 1) ssum += __shfl_xor(ssum, off);
    int lane = tid & 63, wid = tid >> 6;
    if (lane == 0) sred[wid] = ssum;
    __syncthreads();
    if (tid == 0)
        ws[WS_BSP + (size_t)bh*8 + seg] = sred[0] + sred[1] + sred[2] + sred[3];
}

__global__ void avg_k(const float* __restrict__ ws, float* __restrict__ dout)
{
    __shared__ float red[4];
    int tid = threadIdx.x;   // 256 thr
    float v = ws[WS_BSP + tid];
    for (int off = 32; off; off >>= 1) v += __shfl_xor(v, off);
    int lane = tid & 63, wid = tid >> 6;
    if (lane == 0) red[wid] = v;
    __syncthreads();
    if (tid == 0)
        dout[AVG_OFF] = (red[0]+red[1]+red[2]+red[3]) * (1.0f / ((float)BH * (float)NCAND));
}

// ============================================================
// exact top-k threshold via byte-histogram radix (4 passes),
// then stable index-ordered compaction (unchanged).
// ============================================================
__global__ __launch_bounds__(1024) void topk_k(float* __restrict__ ws, int* __restrict__ sel)
{
    __shared__ unsigned keys[NCAND];
    __shared__ int hist[256];
    __shared__ int red[16];
    __shared__ int red2[16];
    __shared__ int bcast;
    __shared__ unsigned bbyte;
    int bh = blockIdx.x, tid = threadIdx.x;
    int lane = tid & 63, wid = tid >> 6;

    for (int j = tid; j < NCAND; j += 1024) {
        unsigned u = __float_as_uint(ws[WS_SC + (size_t)bh*NCAND + j]);
        u ^= (u & 0x80000000u) ? 0xFFFFFFFFu : 0x80000000u;
        keys[j] = u;
    }
    __syncthreads();

    int rem = NKEEP;
    unsigned prefix = 0;
    #pragma unroll
    for (int pass = 0; pass < 4; ++pass) {
        int shift = 24 - 8*pass;
        if (tid < 256) hist[tid] = 0;
        __syncthreads();
        unsigned himask = (pass == 0) ? 0u : (0xFFFFFFFFu << (shift + 8));
        for (int j = tid; j < NCAND; j += 1024) {
            unsigned k = keys[j];
            if ((k & himask) == prefix)
                atomicAdd(&hist[(k >> shift) & 255], 1);
        }
        __syncthreads();
        if (tid == 0) {
            int cum = 0, b = 0;
            for (; b < 255; ++b) {
                if (rem <= cum + hist[b]) break;
                cum += hist[b];
            }
            bcast = cum;
            bbyte = (unsigned)b;
        }
        __syncthreads();
        rem -= bcast;
        prefix |= (bbyte << shift);
        __syncthreads();
    }
    unsigned T = prefix;

    {
        int cnt = 0;
        for (int j = tid; j < NCAND; j += 1024) cnt += (int)(keys[j] < T);
        for (int off = 32; off; off >>= 1) cnt += __shfl_xor(cnt, off);
        if (lane == 0) red[wid] = cnt;
        __syncthreads();
        if (tid == 0) { int c = 0; for (int i = 0; i < 16; ++i) c += red[i]; bcast = c; }
        __syncthreads();
    }
    int c_less = bcast;
    int ttie = NKEEP - c_less;

    int base = tid * 8;
    unsigned kv[8]; int lcnt = 0, ecnt = 0;
    #pragma unroll
    for (int i = 0; i < 8; ++i) {
        kv[i] = keys[base + i];
        lcnt += (int)(kv[i] < T);
        ecnt += (int)(kv[i] == T);
    }
    int li = lcnt, ei = ecnt;
    for (int off = 1; off < 64; off <<= 1) {
        int tl = __shfl_up(li, off);
        int te = __shfl_up(ei, off);
        if (lane >= off) { li += tl; ei += te; }
    }
    __syncthreads();
    if (lane == 63) { red[wid] = li; red2[wid] = ei; }
    __syncthreads();
    int lb = 0, eb = 0;
    for (int w = 0; w < wid; ++w) { lb += red[w]; eb += red2[w]; }
    lb += li - lcnt; eb += ei - ecnt;
    #pragma unroll
    for (int i = 0; i < 8; ++i) {
        bool less = kv[i] < T, eq = kv[i] == T;
        if (less || (eq && eb < ttie)) {
            int pos = lb + (eb < ttie ? eb : ttie);
            sel[(size_t)bh*NKEEP + pos] = base + i;
        }
        lb += (int)less; eb += (int)eq;
    }
}

// ============================================================
// gather k_new / v_new (fp32, exact) into d_out
// ============================================================
__global__ __launch_bounds__(256) void gather_k(const float* __restrict__ past_k,
                                                const float* __restrict__ past_v,
                                                const float* __restrict__ ws,
                                                const int* __restrict__ sel,
                                                float* __restrict__ dout)
{
    int gid = blockIdx.x * 256 + threadIdx.x;
    int row = gid >> 4, lane = gid & 15;
    int bh = row >> 12, r = row & 4095;
    int pos = (r < NANCH) ? r : (NANCH + sel[(size_t)bh*NKEEP + (r - NANCH)]);
    const float *kr, *vr;
    if (pos < NPAST) {
        kr = past_k + ((size_t)bh*NPAST + pos) * DD;
        vr = past_v + ((size_t)bh*NPAST + pos) * DD;
    } else {
        kr = ws + WS_KF + ((size_t)bh*NN + (pos - NPAST)) * DD;
        vr = ws + WS_VF + ((size_t)bh*NN + (pos - NPAST)) * DD;
    }
    float4 kq = *(const float4*)&kr[lane*4];
    float4 vq = *(const float4*)&vr[lane*4];
    *(float4*)&dout[KNEW_OFF + ((size_t)bh*CBUD + r)*DD + lane*4] = kq;
    *(float4*)&dout[VNEW_OFF + ((size_t)bh*CBUD + r)*DD + lane*4] = vq;
}

// ============================================================
// V^T bf16: vt[bh][d][key] from v_new fp32
// ============================================================
__global__ __launch_bounds__(256) void vtrans_k(const float* __restrict__ dout,
                                                unsigned short* __restrict__ vt)
{
    __shared__ unsigned short S[64][65];
    int bh = blockIdx.x >> 6, kt = blockIdx.x & 63;
    int c0 = kt * 64;
    int tid = threadIdx.x;
    int r = tid >> 2, c4 = (tid & 3) * 16;
    const float* src = dout + VNEW_OFF + ((size_t)bh*CBUD + c0 + r)*DD + c4;
    #pragma unroll
    for (int i = 0; i < 4; ++i) {
        float4 f = *(const float4*)&src[i*4];
        S[r][c4 + i*4 + 0] = f2bf(f.x);
        S[r][c4 + i*4 + 1] = f2bf(f.y);
        S[r][c4 + i*4 + 2] = f2bf(f.z);
        S[r][c4 + i*4 + 3] = f2bf(f.w);
    }
    __syncthreads();
    int d = r, k4 = c4;
    uint4 u0, u1;
    u0.x = (unsigned)S[k4+0][d] | ((unsigned)S[k4+1][d] << 16);
    u0.y = (unsigned)S[k4+2][d] | ((unsigned)S[k4+3][d] << 16);
    u0.z = (unsigned)S[k4+4][d] | ((unsigned)S[k4+5][d] << 16);
    u0.w = (unsigned)S[k4+6][d] | ((unsigned)S[k4+7][d] << 16);
    u1.x = (unsigned)S[k4+8][d] | ((unsigned)S[k4+9][d] << 16);
    u1.y = (unsigned)S[k4+10][d] | ((unsigned)S[k4+11][d] << 16);
    u1.z = (unsigned)S[k4+12][d] | ((unsigned)S[k4+13][d] << 16);
    u1.w = (unsigned)S[k4+14][d] | ((unsigned)S[k4+15][d] << 16);
    unsigned short* dst = vt + ((size_t)bh*DD + d)*CBUD + c0 + k4;
    *(uint4*)&dst[0] = u0;
    *(uint4*)&dst[8] = u1;
}

// ============================================================
// MFMA flash attention, swapped QK^T (S^T), lane-local softmax
// in exp2 domain, defer-max, dbuf KV staging (1 barrier/tile),
// conflict-free 8-thr/row staging, setprio on MFMA clusters.
// ============================================================
__global__ __launch_bounds__(256) void attn_mfma(const unsigned short* __restrict__ qb,
                                                 const float* __restrict__ dout,
                                                 const unsigned short* __restrict__ vt,
                                                 unsigned short* __restrict__ ot)
{
    __shared__ char kls[2][8192];
    __shared__ char vls[2][8192];
    __shared__ char pls[4][2048];

    const float SCL = 0.125f * 1.44269504089f;   // scale * log2(e)
    const float THR = 11.5415603f;               // 8 * log2(e)

    int orig = blockIdx.x;
    int bid = (orig & 7) * 64 + (orig >> 3);
    int bh = bid >> 4, qt = bid & 15;
    int b = bh >> 4, h = bh & 15;
    int tid = threadIdx.x;
    int w = tid >> 6, lane = tid & 63;
    int g = lane >> 4, r16 = lane & 15;
    int q0 = qt * 64 + w * 16;

    const unsigned short* qrow = qb + ((size_t)bh*NN + q0 + r16) * DD;
    short8 qa0 = *(const short8*)&qrow[8*g];
    short8 qa1 = *(const short8*)&qrow[32 + 8*g];

    const float* kf = dout + KNEW_OFF + (size_t)bh * CBUD * DD;
    const unsigned short* vtb = vt + (size_t)bh * DD * CBUD;
    char* plw = pls[w];
    int psw = (r16 & 7) << 4;

    // conflict-free staging map: 8 threads/row, 16B each (round-2 pattern)
    int srA = tid >> 3;                 // rows 0..31
    int srB = srA + 32;                 // rows 32..63
    int scb = (tid & 7) * 16;           // byte col 0..112
    int d0  = scb >> 1;                 // element col 0..56
    int sdA = (srA*128 + scb) ^ ((srA & 7) << 4);
    int sdB = (srB*128 + scb) ^ ((srB & 7) << 4);

    f32x4 accd[4];
    #pragma unroll
    for (int dt = 0; dt < 4; ++dt) accd[dt] = 0.f;
    float m = -3.0e38f, l = 0.f;

    // prologue: stage tile 0 into buf 0
    {
        const float* ksA = kf + (size_t)srA * DD + d0;
        const float* ksB = kf + (size_t)srB * DD + d0;
        float4 a0 = *(const float4*)ksA, a1 = *(const float4*)(ksA + 4);
        float4 b0 = *(const float4*)ksB, b1 = *(const float4*)(ksB + 4);
        uint4 kuA, kuB;
        kuA.x = cvtpk(a0.x,a0.y); kuA.y = cvtpk(a0.z,a0.w);
        kuA.z = cvtpk(a1.x,a1.y); kuA.w = cvtpk(a1.z,a1.w);
        kuB.x = cvtpk(b0.x,b0.y); kuB.y = cvtpk(b0.z,b0.w);
        kuB.z = cvtpk(b1.x,b1.y); kuB.w = cvtpk(b1.z,b1.w);
        uint4 vuA = *(const uint4*)(vtb + (size_t)srA*CBUD + d0);
        uint4 vuB = *(const uint4*)(vtb + (size_t)srB*CBUD + d0);
        *(uint4*)&kls[0][sdA] = kuA; *(uint4*)&kls[0][sdB] = kuB;
        *(uint4*)&vls[0][sdA] = vuA; *(uint4*)&vls[0][sdB] = vuB;
    }
    __syncthreads();

    int cur = 0;
    for (int t = 0; t < 64; ++t) {
        float4 a0, a1, b0, b1; uint4 vuA, vuB;
        bool more = (t + 1 < 64);
        if (more) {
            const float* ksA = kf + (size_t)(t+1)*64*DD + (size_t)srA * DD + d0;
            const float* ksB = kf + (size_t)(t+1)*64*DD + (size_t)srB * DD + d0;
            a0 = *(const float4*)ksA; a1 = *(const float4*)(ksA + 4);
            b0 = *(const float4*)ksB; b1 = *(const float4*)(ksB + 4);
            vuA = *(const uint4*)(vtb + (size_t)srA*CBUD + (t+1)*64 + d0);
            vuB = *(const uint4*)(vtb + (size_t)srB*CBUD + (t+1)*64 + d0);
        }

        const char* kb = kls[cur];
        f32x4 sacc[4];
        #pragma unroll
        for (int t4 = 0; t4 < 4; ++t4) sacc[t4] = 0.f;
        __builtin_amdgcn_s_setprio(1);
        #pragma unroll
        for (int t4 = 0; t4 < 4; ++t4) {
            int row = 16*t4 + r16;
            int sw = (r16 & 7) << 4;
            short8 ka0 = *(const short8*)(kb + ((row*128 + g*16) ^ sw));
            short8 ka1 = *(const short8*)(kb + ((row*128 + 64 + g*16) ^ sw));
            sacc[t4] = __builtin_amdgcn_mfma_f32_16x16x32_bf16(ka0, qa0, sacc[t4], 0, 0, 0);
            sacc[t4] = __builtin_amdgcn_mfma_f32_16x16x32_bf16(ka1, qa1, sacc[t4], 0, 0, 0);
        }
        __builtin_amdgcn_s_setprio(0);

        float sv[4][4];
        float smax = -3.0e38f;
        #pragma unroll
        for (int t4 = 0; t4 < 4; ++t4)
            #pragma unroll
            for (int rr = 0; rr < 4; ++rr) {
                sv[t4][rr] = sacc[t4][rr] * SCL;
                smax = fmaxf(smax, sv[t4][rr]);
            }
        smax = fmaxf(smax, __shfl_xor(smax, 16));
        smax = fmaxf(smax, __shfl_xor(smax, 32));

        if (!__all(smax <= m + THR)) {
            float mnew = fmaxf(m, smax);
            float rs = fexp2(m - mnew);
            l *= rs;
            m = mnew;
            float rq0 = __shfl(rs, 20*g + 0);
            float rq1 = __shfl(rs, 20*g + 1);
            float rq2 = __shfl(rs, 20*g + 2);
            float rq3 = __shfl(rs, 20*g + 3);
            #pragma unroll
            for (int dt = 0; dt < 4; ++dt) {
                accd[dt][0] *= rq0; accd[dt][1] *= rq1;
                accd[dt][2] *= rq2; accd[dt][3] *= rq3;
            }
        }

        float ps = 0.f;
        float p[4][4];
        #pragma unroll
        for (int t4 = 0; t4 < 4; ++t4)
            #pragma unroll
            for (int rr = 0; rr < 4; ++rr) {
                p[t4][rr] = fexp2(sv[t4][rr] - m);
                ps += p[t4][rr];
            }
        #pragma unroll
        for (int t4 = 0; t4 < 4; ++t4) {
            unsigned u0 = cvtpk(p[t4][0], p[t4][1]);
            unsigned u1 = cvtpk(p[t4][2], p[t4][3]);
            int cb = (16*t4 + 4*g) * 2;
            *(unsigned*)&plw[(r16*128 + cb)     ^ psw] = u0;
            *(unsigned*)&plw[(r16*128 + cb + 4) ^ psw] = u1;
        }
        ps += __shfl_xor(ps, 16);
        ps += __shfl_xor(ps, 32);
        l += ps;

        short8 pa0 = *(const short8*)&plw[(r16*128 + 16*g)      ^ psw];
        short8 pa1 = *(const short8*)&plw[(r16*128 + 64 + 16*g) ^ psw];
        const char* vb = vls[cur];
        __builtin_amdgcn_s_setprio(1);
        #pragma unroll
        for (int dt = 0; dt < 4; ++dt) {
            int row = dt*16 + r16;
            int sw = (r16 & 7) << 4;
            short8 vb0 = *(const short8*)(vb + ((row*128 + g*16) ^ sw));
            short8 vb1 = *(const short8*)(vb + ((row*128 + 64 + g*16) ^ sw));
            accd[dt] = __builtin_amdgcn_mfma_f32_16x16x32_bf16(pa0, vb0, accd[dt], 0, 0, 0);
            accd[dt] = __builtin_amdgcn_mfma_f32_16x16x32_bf16(pa1, vb1, accd[dt], 0, 0, 0);
        }
        __builtin_amdgcn_s_setprio(0);

        if (more) {
            uint4 kuA, kuB;
            kuA.x = cvtpk(a0.x,a0.y); kuA.y = cvtpk(a0.z,a0.w);
            kuA.z = cvtpk(a1.x,a1.y); kuA.w = cvtpk(a1.z,a1.w);
            kuB.x = cvtpk(b0.x,b0.y); kuB.y = cvtpk(b0.z,b0.w);
            kuB.z = cvtpk(b1.x,b1.y); kuB.w = cvtpk(b1.z,b1.w);
            *(uint4*)&kls[cur^1][sdA] = kuA; *(uint4*)&kls[cur^1][sdB] = kuB;
            *(uint4*)&vls[cur^1][sdA] = vuA; *(uint4*)&vls[cur^1][sdB] = vuB;
        }
        __syncthreads();
        cur ^= 1;
    }

    float ivl = 1.0f / l;
    float iq0 = __shfl(ivl, 20*g + 0);
    float iq1 = __shfl(ivl, 20*g + 1);
    float iq2 = __shfl(ivl, 20*g + 2);
    float iq3 = __shfl(ivl, 20*g + 3);
    float iq[4] = {iq0, iq1, iq2, iq3};
    #pragma unroll
    for (int dt = 0; dt < 4; ++dt) {
        #pragma unroll
        for (int rr = 0; rr < 4; ++rr) {
            int q = q0 + 4*g + rr;
            int mrow = b*1024 + q;
            int d = dt*16 + r16;
            size_t tile = (size_t)(mrow >> 7) * 16 + h;
            int inner = ((mrow & 127)*128 + d*2) ^ ((mrow & 7) << 4);
            *(unsigned short*)((char*)ot + tile*TILEB + inner) = f2bf(accd[dt][rr] * iq[rr]);
        }
    }
}

// ============================================================
extern "C" void kernel_launch(void* const* d_in, const int* in_sizes, int n_in,
                              void* d_out, int out_size, void* d_ws, size_t ws_size,
                              hipStream_t stream)
{
    (void)in_sizes; (void)n_in; (void)out_size; (void)ws_size;
    const float* x      = (const float*)d_in[0];
    const float* past_k = (const float*)d_in[1];
    const float* past_v = (const float*)d_in[2];
    const float* qkv_w  = (const float*)d_in[3];
    const float* qkv_b  = (const float*)d_in[4];
    const float* proj_w = (const float*)d_in[5];
    const float* proj_b = (const float*)d_in[6];
    float* out = (float*)d_out;
    float* ws  = (float*)d_ws;
    int*   sel = (int*)(ws + WS_SEL);
    unsigned short* xt   = (unsigned short*)(ws + WS_XT);
    unsigned short* wqvt = (unsigned short*)(ws + WS_WQVT);
    unsigned short* wpt  = (unsigned short*)(ws + WS_WPT);
    unsigned short* qbp  = (unsigned short*)(ws + WS_QB);
    unsigned short* vtp  = (unsigned short*)(ws + WS_VT);
    unsigned short* otp  = (unsigned short*)(ws + WS_OT);

    conv_tile<<<1024, 256, 0, stream>>>(x, xt);
    conv_wqv<<<1024, 256, 0, stream>>>(qkv_w, wqvt);
    kf_gemm<<<dim3(16, 32), 256, 0, stream>>>(x, qkv_w, qkv_b, ws);
    mfma_gemm<0><<<dim3(16, 16), 256, 0, stream>>>(xt, wqvt, qkv_b, ws);
    meandir_part<<<dim3(32, 8), 256, 0, stream>>>(past_k, ws);
    meandir_red<<<32, 64, 0, stream>>>(ws);
    scores_part<<<dim3(32, 8), 256, 0, stream>>>(past_k, ws);
    avg_k<<<1, 256, 0, stream>>>(ws, out);
    topk_k<<<32, 1024, 0, stream>>>(ws, sel);
    gather_k<<<8192, 256, 0, stream>>>(past_k, past_v, ws, sel, out);
    vtrans_k<<<2048, 256, 0, stream>>>(out, vtp);
    conv_tile<<<512, 256, 0, stream>>>(proj_w, wpt);
    attn_mfma<<<512, 256, 0, stream>>>(qbp, out, vtp, otp);
    mfma_gemm<1><<<dim3(8, 16), 256, 0, stream>>>(otp, wpt, proj_b, out);
}